// Round 1
// baseline (8712.690 us; speedup 1.0000x reference)
//
#include <hip/hip_runtime.h>
#include <stdint.h>

typedef unsigned int u32;

#define FDIM  128
#define NNODE 25000   // LDS sizing only; runtime N asserted <= this by problem spec
#define WG    1024

// ---------- monotone float<->uint encoding (order-preserving) ----------
__device__ __forceinline__ u32 enc_f32(float f){
  u32 u = __float_as_uint(f);
  return (u & 0x80000000u) ? ~u : (u | 0x80000000u);
}
__device__ __forceinline__ float dec_f32(u32 u){
  u = (u & 0x80000000u) ? (u ^ 0x80000000u) : ~u;
  return __uint_as_float(u);
}

// ---------- XLA CPU GenerateVF32Exp replica ----------
// Variant: fused-FMA Horner polynomial, UNFUSED range-reduction (mul+sub),
// fx via fused fma, 2^n via exponent bits. (Round-1 guess; alt variants held back.)
__device__ __forceinline__ float xla_expf(float x){
  x = fminf(x,  88.3762626647950f);
  x = fmaxf(x, -88.3762626647949f);
  float fx = floorf(fmaf(x, 1.44269504088896341f, 0.5f));
  float tmp = __fmul_rn(fx, 0.693359375f);
  float zz  = __fmul_rn(fx, -2.12194440e-4f);
  x = __fsub_rn(x, tmp);
  x = __fsub_rn(x, zz);
  float z2 = __fmul_rn(x, x);
  float y = fmaf(1.9875691500E-4f, x, 1.3981999507E-3f);
  y = fmaf(y, x, 8.3334519073E-3f);
  y = fmaf(y, x, 4.1665795894E-2f);
  y = fmaf(y, x, 1.6666665459E-1f);
  y = fmaf(y, x, 5.0000001201E-1f);
  y = fmaf(y, z2, x);
  y = __fadd_rn(y, 1.0f);
  int n = (int)fx;
  float p2n = __uint_as_float((u32)(n + 127) << 23);
  return __fmul_rn(y, p2n);
}

// ---------- raw edge scores + per-dst max/count ----------
// Dot variant: strict sequential k=0..127, UNFUSED mul+add (Eigen gebp, AVX no-FMA guess).
__global__ void k_raw(const float* __restrict__ x, const int* __restrict__ ei,
                      const float* __restrict__ wsrc, const float* __restrict__ wdst,
                      const float* __restrict__ b,
                      float* __restrict__ raw, u32* __restrict__ m_enc, u32* __restrict__ counts,
                      int N_, int E_)
{
  int e = blockIdx.x * blockDim.x + threadIdx.x;
  if (e >= E_) return;
  int s = ei[e], d = ei[E_ + e];
  const float* xs = x + (size_t)s * FDIM;
  const float* xd = x + (size_t)d * FDIM;
  float accs = 0.f, accd = 0.f;
  for (int k = 0; k < FDIM; ++k) accs = __fadd_rn(accs, __fmul_rn(xs[k], wsrc[k]));
  for (int k = 0; k < FDIM; ++k) accd = __fadd_rn(accd, __fmul_rn(xd[k], wdst[k]));
  float r = __fadd_rn(__fadd_rn(accs, accd), b[0]);
  raw[e] = r;
  atomicMax(&m_enc[d], enc_f32(r));
  atomicAdd(&counts[d], 1u);
}

// ---------- exclusive scan of per-dst counts (single block) ----------
__global__ __launch_bounds__(WG) void k_scan_counts(const u32* __restrict__ counts,
                                                    u32* __restrict__ dstoff, int N_)
{
  __shared__ u32 lds[WG];
  int t = threadIdx.x;
  int chunk = (N_ + WG - 1) / WG;
  int lo = t * chunk; if (lo > N_) lo = N_;
  int hi = lo + chunk; if (hi > N_) hi = N_;
  u32 s = 0;
  for (int v = lo; v < hi; ++v) s += counts[v];
  lds[t] = s; __syncthreads();
  for (int off = 1; off < WG; off <<= 1) {
    u32 a = (t >= off) ? lds[t - off] : 0u;
    __syncthreads();
    lds[t] += a;
    __syncthreads();
  }
  u32 run = lds[t] - s;
  for (int v = lo; v < hi; ++v) { dstoff[v] = run; run += counts[v]; }
}

// ---------- key builders ----------
__global__ void k_key_dst(const int* __restrict__ ei, u32* __restrict__ kA, u32* __restrict__ vA, int E_)
{
  int e = blockIdx.x * blockDim.x + threadIdx.x;
  if (e >= E_) return;
  kA[e] = (u32)ei[E_ + e];
  vA[e] = (u32)e;
}
__global__ void k_key_score(const float* __restrict__ score, u32* __restrict__ kA, u32* __restrict__ vA, int E_)
{
  int e = blockIdx.x * blockDim.x + threadIdx.x;
  if (e >= E_) return;
  kA[e] = ~enc_f32(score[e]);   // ascending sort => descending score, stable => index asc on ties
  vA[e] = (u32)e;
}

// ---------- stable LSD radix sort, single block, 4-bit digits ----------
__global__ __launch_bounds__(256) void k_radix(u32* kA, u32* vA, u32* kB, u32* vB, int n, int npasses)
{
  __shared__ u32 hist[256 * 16];
  __shared__ u32 dstart[16];
  __shared__ u32 digtot[16];
  const int t = threadIdx.x;
  const int chunk = (n + 255) >> 8;
  int lo = t * chunk; if (lo > n) lo = n;
  int hi = lo + chunk; if (hi > n) hi = n;
  u32 *ka = kA, *va = vA, *kb = kB, *vb = vB;
  for (int p = 0; p < npasses; ++p) {
    const int sh = p * 4;
    for (int d = 0; d < 16; ++d) hist[t * 16 + d] = 0;
    __syncthreads();
    for (int i = lo; i < hi; ++i) { u32 d = (ka[i] >> sh) & 15u; hist[t * 16 + d]++; }
    __syncthreads();
    if (t < 16) {
      u32 run = 0;
      for (int q = 0; q < 256; ++q) { u32 c = hist[q * 16 + t]; hist[q * 16 + t] = run; run += c; }
      digtot[t] = run;
    }
    __syncthreads();
    if (t == 0) { u32 run = 0; for (int d = 0; d < 16; ++d) { dstart[d] = run; run += digtot[d]; } }
    __syncthreads();
    for (int i = lo; i < hi; ++i) {
      u32 k = ka[i]; u32 d = (k >> sh) & 15u;
      u32 pos = dstart[d] + hist[t * 16 + d];
      hist[t * 16 + d]++;
      kb[pos] = k; vb[pos] = va[i];
    }
    __syncthreads();
    { u32* tk = ka; ka = kb; kb = tk; u32* tv = va; va = vb; vb = tv; }
  }
}

// ---------- softmax scores: denom accumulated sequentially in edge-id order ----------
__global__ void k_scores(const float* __restrict__ raw, const u32* __restrict__ m_enc,
                         const u32* __restrict__ counts, const u32* __restrict__ dstoff,
                         const u32* __restrict__ ebydst, float* __restrict__ score, int N_)
{
  int v = blockIdx.x * blockDim.x + threadIdx.x;
  if (v >= N_) return;
  u32 c = counts[v];
  if (c == 0) return;
  u32 off = dstoff[v];
  float m = dec_f32(m_enc[v]);
  float denom = 0.f;
  for (u32 i = 0; i < c; ++i) {
    u32 e = ebydst[off + i];
    denom = __fadd_rn(denom, xla_expf(__fsub_rn(raw[e], m)));
  }
  for (u32 i = 0; i < c; ++i) {
    u32 e = ebydst[off + i];
    float z = xla_expf(__fsub_rn(raw[e], m));
    score[e] = __fadd_rn(__fdiv_rn(z, denom), 0.5f);
  }
}

// ---------- greedy matching (priority = sorted position) + cluster ids ----------
__global__ __launch_bounds__(WG) void k_match(
    const int* __restrict__ ei, const float* __restrict__ score, const u32* __restrict__ sidx,
    u32* __restrict__ srcS, u32* __restrict__ dstS, float* __restrict__ scoreS,
    u32* liveA, u32* liveB, u32* __restrict__ chosen,
    int* __restrict__ cluster, u32* __restrict__ pairA, u32* __restrict__ pairB,
    float* __restrict__ cscore, u32* __restrict__ cnts, int N_, int E_)
{
  __shared__ u32 node_min[NNODE];
  __shared__ unsigned char matched[NNODE];
  __shared__ u32 lds[WG];
  __shared__ u32 s_nlive, s_next;
  const int t = threadIdx.x;

  for (int i = t; i < N_; i += WG) { node_min[i] = 0xFFFFFFFFu; matched[i] = 0; }
  for (int k = t; k < E_; k += WG) {
    u32 e = sidx[k];
    srcS[k] = (u32)ei[e];
    dstS[k] = (u32)ei[E_ + e];
    scoreS[k] = score[e];
    liveA[k] = (u32)k;
    chosen[k] = 0u;
  }
  if (t == 0) { s_nlive = (u32)E_; s_next = 0u; }
  __syncthreads();

  u32* LA = liveA; u32* LB = liveB;
  int guard = 0;
  while (true) {
    u32 nl = s_nlive;
    if (nl == 0u || ++guard > E_ + 2) break;
    for (u32 i = (u32)t; i < nl; i += WG) {
      u32 k = LA[i];
      atomicMin(&node_min[srcS[k]], k);
      atomicMin(&node_min[dstS[k]], k);
    }
    __syncthreads();
    for (u32 i = (u32)t; i < nl; i += WG) {
      u32 k = LA[i]; u32 s = srcS[k], d = dstS[k];
      if (node_min[s] == k && node_min[d] == k) { chosen[k] = 1u; matched[s] = 1; matched[d] = 1; }
    }
    __syncthreads();
    for (u32 i = (u32)t; i < nl; i += WG) {
      u32 k = LA[i];
      if (!matched[srcS[k]] && !matched[dstS[k]]) { u32 p = atomicAdd(&s_next, 1u); LB[p] = k; }
    }
    __syncthreads();
    for (int i = t; i < N_; i += WG) node_min[i] = 0xFFFFFFFFu;
    if (t == 0) { s_nlive = s_next; s_next = 0u; }
    { u32* tmp = LA; LA = LB; LB = tmp; }
    __syncthreads();
  }

  // ---- chosen-edge prefix scan (stable, contiguous chunks) -> pair-cluster ids ----
  int chunkE = (E_ + WG - 1) / WG;
  int lo = t * chunkE; if (lo > E_) lo = E_;
  int hi = lo + chunkE; if (hi > E_) hi = E_;
  u32 s = 0;
  for (int k = lo; k < hi; ++k) s += chosen[k];
  lds[t] = s; __syncthreads();
  for (int off = 1; off < WG; off <<= 1) {
    u32 a = (t >= off) ? lds[t - off] : 0u; __syncthreads();
    lds[t] += a; __syncthreads();
  }
  u32 totalC = lds[WG - 1];
  u32 run = lds[t] - s;
  for (int k = lo; k < hi; ++k) {
    if (chosen[k]) {
      u32 c = run++;
      u32 sv = srcS[k], dv = dstS[k];
      cluster[sv] = (int)c; cluster[dv] = (int)c;
      pairA[c] = sv; pairB[c] = dv; cscore[c] = scoreS[k];
    }
  }
  __syncthreads();

  // ---- singleton ids: cnt + cumsum(unmatched) over node order ----
  int chunkN = (N_ + WG - 1) / WG;
  lo = t * chunkN; if (lo > N_) lo = N_;
  hi = lo + chunkN; if (hi > N_) hi = N_;
  s = 0;
  for (int v = lo; v < hi; ++v) s += (matched[v] ? 0u : 1u);
  lds[t] = s; __syncthreads();
  for (int off = 1; off < WG; off <<= 1) {
    u32 a = (t >= off) ? lds[t - off] : 0u; __syncthreads();
    lds[t] += a; __syncthreads();
  }
  u32 totalL = lds[WG - 1];
  run = lds[t] - s;
  for (int v = lo; v < hi; ++v) {
    if (!matched[v]) {
      u32 c = totalC + run++;
      cluster[v] = (int)c;
      pairA[c] = (u32)v; pairB[c] = (u32)v; cscore[c] = 1.0f;
    }
  }
  if (t == 0) cnts[3] = totalC + totalL;
}

// ---------- outputs ----------
__global__ void k_newx(const float* __restrict__ x, const u32* __restrict__ pairA,
                       const u32* __restrict__ pairB, const float* __restrict__ cscore,
                       const u32* __restrict__ cnts, float* __restrict__ out, int N_)
{
  int j = blockIdx.x * blockDim.x + threadIdx.x;
  int total = N_ * (FDIM / 4);
  if (j >= total) return;
  u32 c = (u32)(j >> 5);
  int q = (j & 31) * 4;
  if (c >= cnts[3]) return;   // rows beyond num_clusters stay zero (memset)
  u32 a = pairA[c], bb = pairB[c];
  float cs = cscore[c];
  const float4 va = *(const float4*)(x + (size_t)a * FDIM + q);
  float4 o;
  if (a == bb) {
    o.x = __fmul_rn(va.x, cs); o.y = __fmul_rn(va.y, cs);
    o.z = __fmul_rn(va.z, cs); o.w = __fmul_rn(va.w, cs);
  } else {
    const float4 vb = *(const float4*)(x + (size_t)bb * FDIM + q);
    o.x = __fmul_rn(__fadd_rn(va.x, vb.x), cs);
    o.y = __fmul_rn(__fadd_rn(va.y, vb.y), cs);
    o.z = __fmul_rn(__fadd_rn(va.z, vb.z), cs);
    o.w = __fmul_rn(__fadd_rn(va.w, vb.w), cs);
  }
  *(float4*)(out + (size_t)c * FDIM + q) = o;
}

__global__ void k_newei(const int* __restrict__ ei, const int* __restrict__ cluster,
                        const u32* __restrict__ cnts, float* __restrict__ out, int N_, int E_)
{
  int e = blockIdx.x * blockDim.x + threadIdx.x;
  if (e >= E_) return;
  int c0 = cluster[ei[e]];
  int c1 = cluster[ei[E_ + e]];
  if (c0 == c1) { c0 = -1; c1 = -1; }
  size_t base = (size_t)N_ * FDIM;
  out[base + e] = (float)c0;
  out[base + E_ + e] = (float)c1;
  if (e == 0) out[base + 2 * (size_t)E_ + N_] = (float)cnts[3];  // num_clusters
}

extern "C" void kernel_launch(void* const* d_in, const int* in_sizes, int n_in,
                              void* d_out, int out_size, void* d_ws, size_t ws_size,
                              hipStream_t stream)
{
  const float* x    = (const float*)d_in[0];
  const int*   ei   = (const int*)d_in[1];
  const float* wsrc = (const float*)d_in[3];
  const float* wdst = (const float*)d_in[4];
  const float* b    = (const float*)d_in[5];
  const int N = in_sizes[0] / FDIM;
  const int E = in_sizes[1] / 2;

  // workspace layout (u32 words)
  u32* w = (u32*)d_ws;
  float* raw   = (float*)w;      w += E;
  float* score = (float*)w;      w += E;
  u32* kA = w;                   w += E;
  u32* vA = w;                   w += E;
  u32* kB = w;                   w += E;
  u32* vB = w;                   w += E;
  u32* m_enc  = w;               w += N;
  u32* counts = w;               w += N;
  u32* dstoff = w;               w += N;
  int* cluster = (int*)w;        w += N;
  u32* pairA = w;                w += N;
  u32* pairB = w;                w += N;
  float* cscore = (float*)w;     w += N;
  u32* cnts = w;                 w += 16;

  // d_out doubles as scratch for match-phase arrays (dead before the output memset)
  u32* liveA  = (u32*)d_out;
  u32* liveB  = liveA + E;
  u32* chosen = liveA + 2 * (size_t)E;
  u32* srcS   = liveA + 3 * (size_t)E;
  u32* dstS   = liveA + 4 * (size_t)E;
  float* scoreS = (float*)(liveA + 5 * (size_t)E);

  const int TB = 256;
  const int gridE = (E + TB - 1) / TB;
  const int gridN = (N + TB - 1) / TB;

  hipMemsetAsync(m_enc, 0, (size_t)N * 4, stream);
  hipMemsetAsync(counts, 0, (size_t)N * 4, stream);
  hipMemsetAsync(cnts, 0, 64, stream);

  k_raw<<<gridE, TB, 0, stream>>>(x, ei, wsrc, wdst, b, raw, m_enc, counts, N, E);
  k_scan_counts<<<1, WG, 0, stream>>>(counts, dstoff, N);

  // stable sort edges by dst (16-bit key -> 4 passes), result ids in vA
  k_key_dst<<<gridE, TB, 0, stream>>>(ei, kA, vA, E);
  k_radix<<<1, 256, 0, stream>>>(kA, vA, kB, vB, E, 4);

  k_scores<<<gridN, TB, 0, stream>>>(raw, m_enc, counts, dstoff, vA, score, N);

  // stable sort by descending score (32-bit key -> 8 passes), result ids in vA
  k_key_score<<<gridE, TB, 0, stream>>>(score, kA, vA, E);
  k_radix<<<1, 256, 0, stream>>>(kA, vA, kB, vB, E, 8);

  k_match<<<1, WG, 0, stream>>>(ei, score, vA, srcS, dstS, scoreS,
                                liveA, liveB, chosen,
                                cluster, pairA, pairB, cscore, cnts, N, E);

  hipMemsetAsync(d_out, 0, (size_t)out_size * 4, stream);  // new_x tail rows + new_batch = 0

  k_newx<<<(N * (FDIM / 4) + TB - 1) / TB, TB, 0, stream>>>(x, pairA, pairB, cscore, cnts, (float*)d_out, N);
  k_newei<<<gridE, TB, 0, stream>>>(ei, cluster, cnts, (float*)d_out, N, E);
}

// Round 2
// 1418.976 us; speedup vs baseline: 6.1401x; 6.1401x over previous
//
#include <hip/hip_runtime.h>
#include <stdint.h>

typedef unsigned int u32;
typedef unsigned long long u64;
typedef unsigned short u16;

#define FDIM  128
#define NNODE 25000   // LDS sizing; N <= this
#define WG    1024
#define RB    256     // radix block threads
#define EPT   16      // radix elements per thread
#define RCHUNK (RB*EPT) // 4096 elements per radix block

// ---------- monotone float<->uint encoding (order-preserving) ----------
__device__ __forceinline__ u32 enc_f32(float f){
  u32 u = __float_as_uint(f);
  return (u & 0x80000000u) ? ~u : (u | 0x80000000u);
}
__device__ __forceinline__ float dec_f32(u32 u){
  u = (u & 0x80000000u) ? (u ^ 0x80000000u) : ~u;
  return __uint_as_float(u);
}

// ---------- XLA CPU GenerateVF32Exp replica (DO NOT TOUCH - validated r1) ----------
__device__ __forceinline__ float xla_expf(float x){
  x = fminf(x,  88.3762626647950f);
  x = fmaxf(x, -88.3762626647949f);
  float fx = floorf(fmaf(x, 1.44269504088896341f, 0.5f));
  float tmp = __fmul_rn(fx, 0.693359375f);
  float zz  = __fmul_rn(fx, -2.12194440e-4f);
  x = __fsub_rn(x, tmp);
  x = __fsub_rn(x, zz);
  float z2 = __fmul_rn(x, x);
  float y = fmaf(1.9875691500E-4f, x, 1.3981999507E-3f);
  y = fmaf(y, x, 8.3334519073E-3f);
  y = fmaf(y, x, 4.1665795894E-2f);
  y = fmaf(y, x, 1.6666665459E-1f);
  y = fmaf(y, x, 5.0000001201E-1f);
  y = fmaf(y, z2, x);
  y = __fadd_rn(y, 1.0f);
  int n = (int)fx;
  float p2n = __uint_as_float((u32)(n + 127) << 23);
  return __fmul_rn(y, p2n);
}

// ---------- raw edge scores + per-dst max/count ----------
// Strict sequential k-order, unfused mul+add (bit-identical to r1; float4 is a pure
// load-width change, component order x,y,z,w preserves the scalar sequence).
__global__ __launch_bounds__(256) void k_raw(const float* __restrict__ x, const int* __restrict__ ei,
                      const float* __restrict__ wsrc, const float* __restrict__ wdst,
                      const float* __restrict__ b,
                      float* __restrict__ raw, u32* __restrict__ m_enc, u32* __restrict__ counts,
                      int N_, int E_)
{
  __shared__ float4 w4[64];
  int t = threadIdx.x;
  if (t < 32) w4[t] = ((const float4*)wsrc)[t];
  else if (t < 64) w4[t] = ((const float4*)wdst)[t - 32];
  __syncthreads();
  int e = blockIdx.x * blockDim.x + t;
  if (e >= E_) return;
  int s = ei[e], d = ei[E_ + e];
  const float4* xs = (const float4*)(x + (size_t)s * FDIM);
  const float4* xd = (const float4*)(x + (size_t)d * FDIM);
  float accs = 0.f, accd = 0.f;
  #pragma unroll 4
  for (int k = 0; k < 32; ++k) {
    float4 v = xs[k], w = w4[k];
    accs = __fadd_rn(accs, __fmul_rn(v.x, w.x));
    accs = __fadd_rn(accs, __fmul_rn(v.y, w.y));
    accs = __fadd_rn(accs, __fmul_rn(v.z, w.z));
    accs = __fadd_rn(accs, __fmul_rn(v.w, w.w));
  }
  #pragma unroll 4
  for (int k = 0; k < 32; ++k) {
    float4 v = xd[k], w = w4[k + 32];
    accd = __fadd_rn(accd, __fmul_rn(v.x, w.x));
    accd = __fadd_rn(accd, __fmul_rn(v.y, w.y));
    accd = __fadd_rn(accd, __fmul_rn(v.z, w.z));
    accd = __fadd_rn(accd, __fmul_rn(v.w, w.w));
  }
  float r = __fadd_rn(__fadd_rn(accs, accd), b[0]);
  raw[e] = r;
  atomicMax(&m_enc[d], enc_f32(r));
  atomicAdd(&counts[d], 1u);
}

// ---------- exclusive scan of per-dst counts (single block) ----------
__global__ __launch_bounds__(WG) void k_scan_counts(const u32* __restrict__ counts,
                                                    u32* __restrict__ dstoff, int N_)
{
  __shared__ u32 lds[WG];
  int t = threadIdx.x;
  int chunk = (N_ + WG - 1) / WG;
  int lo = t * chunk; if (lo > N_) lo = N_;
  int hi = lo + chunk; if (hi > N_) hi = N_;
  u32 s = 0;
  for (int v = lo; v < hi; ++v) s += counts[v];
  lds[t] = s; __syncthreads();
  for (int off = 1; off < WG; off <<= 1) {
    u32 a = (t >= off) ? lds[t - off] : 0u;
    __syncthreads();
    lds[t] += a;
    __syncthreads();
  }
  u32 run = lds[t] - s;
  for (int v = lo; v < hi; ++v) { dstoff[v] = run; run += counts[v]; }
}

// ---------- key builders ----------
__global__ void k_key_dst(const int* __restrict__ ei, u32* __restrict__ kA, u32* __restrict__ vA, int E_)
{
  int e = blockIdx.x * blockDim.x + threadIdx.x;
  if (e >= E_) return;
  kA[e] = (u32)ei[E_ + e];
  vA[e] = (u32)e;
}
__global__ void k_key_score(const float* __restrict__ score, u32* __restrict__ kA, u32* __restrict__ vA, int E_)
{
  int e = blockIdx.x * blockDim.x + threadIdx.x;
  if (e >= E_) return;
  kA[e] = ~enc_f32(score[e]);   // ascending => descending score; stable => edge id asc on ties
  vA[e] = (u32)e;
}

// ---------- multi-block stable LSD radix (8-bit digits) ----------
__global__ __launch_bounds__(RB) void k_rhist(const u32* __restrict__ key, u32* __restrict__ hist,
                                              int n, int nb, int shift)
{
  __shared__ u32 h[256];
  int t = threadIdx.x, b = blockIdx.x;
  h[t] = 0; __syncthreads();
  int lo = b * RCHUNK + t * EPT;
  int hi = lo + EPT; if (hi > n) hi = n;
  for (int i = lo; i < hi; ++i) atomicAdd(&h[(key[i] >> shift) & 255u], 1u);
  __syncthreads();
  hist[(size_t)t * nb + b] = h[t];   // digit-major layout
}

__global__ __launch_bounds__(WG) void k_rscan(u32* __restrict__ a, int m)
{
  __shared__ u32 lds[WG];
  int t = threadIdx.x;
  int chunk = (m + WG - 1) / WG;
  int lo = t * chunk; if (lo > m) lo = m;
  int hi = lo + chunk; if (hi > m) hi = m;
  u32 s = 0;
  for (int i = lo; i < hi; ++i) s += a[i];
  lds[t] = s; __syncthreads();
  for (int off = 1; off < WG; off <<= 1) {
    u32 v = (t >= off) ? lds[t - off] : 0u;
    __syncthreads();
    lds[t] += v;
    __syncthreads();
  }
  u32 run = lds[t] - s;
  for (int i = lo; i < hi; ++i) { u32 c = a[i]; a[i] = run; run += c; }
}

// stable scatter: per-(thread,digit) u16 local ranks + per-digit global base
__global__ __launch_bounds__(RB) void k_rscat(const u32* __restrict__ ka, const u32* __restrict__ va,
                                              u32* __restrict__ kb, u32* __restrict__ vb,
                                              const u32* __restrict__ base, int n, int nb, int shift)
{
  __shared__ u16 h[RB][258];     // [thread][digit], padded
  __shared__ u32 gbase[256];
  int t = threadIdx.x, b = blockIdx.x;
  for (int i = t; i < RB * 258 / 2; i += RB) ((u32*)h)[i] = 0u;
  __syncthreads();
  int lo = b * RCHUNK + t * EPT;
  int hi = lo + EPT; if (hi > n) hi = n;
  for (int i = lo; i < hi; ++i) { u32 d = (ka[i] >> shift) & 255u; h[t][d]++; }
  __syncthreads();
  { // thread t owns digit t: exclusive prefix over threads (local ranks <= 4096, fits u16)
    u32 run = 0;
    for (int q = 0; q < RB; ++q) { u16 c = h[q][t]; h[q][t] = (u16)run; run += c; }
    gbase[t] = base[(size_t)t * nb + b];
  }
  __syncthreads();
  for (int i = lo; i < hi; ++i) {
    u32 k = ka[i]; u32 d = (k >> shift) & 255u;
    u32 p = gbase[d] + (u32)h[t][d];
    h[t][d]++;
    kb[p] = k; vb[p] = va[i];
  }
}

// ---------- softmax scores: denom accumulated sequentially in edge-id order ----------
__global__ void k_scores(const float* __restrict__ raw, const u32* __restrict__ m_enc,
                         const u32* __restrict__ counts, const u32* __restrict__ dstoff,
                         const u32* __restrict__ ebydst, float* __restrict__ score, int N_)
{
  int v = blockIdx.x * blockDim.x + threadIdx.x;
  if (v >= N_) return;
  u32 c = counts[v];
  if (c == 0) return;
  u32 off = dstoff[v];
  float m = dec_f32(m_enc[v]);
  float denom = 0.f;
  for (u32 i = 0; i < c; ++i) {
    u32 e = ebydst[off + i];
    denom = __fadd_rn(denom, xla_expf(__fsub_rn(raw[e], m)));
  }
  for (u32 i = 0; i < c; ++i) {
    u32 e = ebydst[off + i];
    float z = xla_expf(__fsub_rn(raw[e], m));
    score[e] = __fadd_rn(__fdiv_rn(z, denom), 0.5f);
  }
}

// ---------- greedy matching (priority = sorted rank) + cluster ids ----------
__global__ __launch_bounds__(WG) void k_match(
    const int* __restrict__ ei, const float* __restrict__ score, const u32* __restrict__ sidx,
    u64* __restrict__ srcdstS, u32* liveA, u32* liveB, u32* __restrict__ chosen,
    int* __restrict__ cluster, u32* __restrict__ pairA, u32* __restrict__ pairB,
    float* __restrict__ cscore, u32* __restrict__ cnts, int N_, int E_)
{
  __shared__ u32 node_min[NNODE];
  __shared__ unsigned char matched[NNODE];
  __shared__ u32 lds[WG];
  __shared__ u32 s_nlive, s_next;
  const int t = threadIdx.x;

  for (int i = t; i < N_; i += WG) { node_min[i] = 0xFFFFFFFFu; matched[i] = 0; }
  for (int k = t; k < E_; k += WG) {
    u32 e = sidx[k];
    srcdstS[k] = (u64)(u32)ei[e] | ((u64)(u32)ei[E_ + e] << 32);
    chosen[k] = 0u;
  }
  if (t == 0) s_next = 0u;
  __syncthreads();

  // ---- round 1: live set == all edges (no list materialization) ----
  for (int k = t; k < E_; k += WG) {
    u64 sd = srcdstS[k];
    atomicMin(&node_min[(u32)sd], (u32)k);
    atomicMin(&node_min[(u32)(sd >> 32)], (u32)k);
  }
  __syncthreads();
  for (int k = t; k < E_; k += WG) {
    u64 sd = srcdstS[k]; u32 s = (u32)sd, d = (u32)(sd >> 32);
    if (node_min[s] == (u32)k && node_min[d] == (u32)k) { chosen[k] = 1u; matched[s] = 1; matched[d] = 1; }
  }
  __syncthreads();
  for (int k = t; k < E_; k += WG) {
    u64 sd = srcdstS[k];
    if (!matched[(u32)sd] && !matched[(u32)(sd >> 32)]) { u32 p = atomicAdd(&s_next, 1u); liveA[p] = (u32)k; }
  }
  __syncthreads();
  for (int i = t; i < N_; i += WG) node_min[i] = 0xFFFFFFFFu;
  if (t == 0) { s_nlive = s_next; s_next = 0u; }
  __syncthreads();

  u32* LA = liveA; u32* LB = liveB;
  int guard = 0;
  while (true) {
    u32 nl = s_nlive;
    if (nl == 0u || ++guard > E_ + 2) break;
    for (u32 i = (u32)t; i < nl; i += WG) {
      u32 k = LA[i]; u64 sd = srcdstS[k];
      atomicMin(&node_min[(u32)sd], k);
      atomicMin(&node_min[(u32)(sd >> 32)], k);
    }
    __syncthreads();
    for (u32 i = (u32)t; i < nl; i += WG) {
      u32 k = LA[i]; u64 sd = srcdstS[k]; u32 s = (u32)sd, d = (u32)(sd >> 32);
      if (node_min[s] == k && node_min[d] == k) { chosen[k] = 1u; matched[s] = 1; matched[d] = 1; }
    }
    __syncthreads();
    for (u32 i = (u32)t; i < nl; i += WG) {
      u32 k = LA[i]; u64 sd = srcdstS[k];
      if (!matched[(u32)sd] && !matched[(u32)(sd >> 32)]) { u32 p = atomicAdd(&s_next, 1u); LB[p] = k; }
    }
    __syncthreads();
    for (int i = t; i < N_; i += WG) node_min[i] = 0xFFFFFFFFu;
    if (t == 0) { s_nlive = s_next; s_next = 0u; }
    { u32* tmp = LA; LA = LB; LB = tmp; }
    __syncthreads();
  }

  // ---- chosen-edge prefix scan (stable, contiguous chunks) -> pair-cluster ids ----
  int chunkE = (E_ + WG - 1) / WG;
  int lo = t * chunkE; if (lo > E_) lo = E_;
  int hi = lo + chunkE; if (hi > E_) hi = E_;
  u32 s = 0;
  for (int k = lo; k < hi; ++k) s += chosen[k];
  lds[t] = s; __syncthreads();
  for (int off = 1; off < WG; off <<= 1) {
    u32 a = (t >= off) ? lds[t - off] : 0u; __syncthreads();
    lds[t] += a; __syncthreads();
  }
  u32 totalC = lds[WG - 1];
  u32 run = lds[t] - s;
  for (int k = lo; k < hi; ++k) {
    if (chosen[k]) {
      u32 c = run++;
      u64 sd = srcdstS[k];
      u32 sv = (u32)sd, dv = (u32)(sd >> 32);
      cluster[sv] = (int)c; cluster[dv] = (int)c;
      pairA[c] = sv; pairB[c] = dv;
      cscore[c] = score[sidx[k]];
    }
  }
  __syncthreads();

  // ---- singleton ids: cnt + cumsum(unmatched) over node order ----
  int chunkN = (N_ + WG - 1) / WG;
  lo = t * chunkN; if (lo > N_) lo = N_;
  hi = lo + chunkN; if (hi > N_) hi = N_;
  s = 0;
  for (int v = lo; v < hi; ++v) s += (matched[v] ? 0u : 1u);
  lds[t] = s; __syncthreads();
  for (int off = 1; off < WG; off <<= 1) {
    u32 a = (t >= off) ? lds[t - off] : 0u; __syncthreads();
    lds[t] += a; __syncthreads();
  }
  u32 totalL = lds[WG - 1];
  run = lds[t] - s;
  for (int v = lo; v < hi; ++v) {
    if (!matched[v]) {
      u32 c = totalC + run++;
      cluster[v] = (int)c;
      pairA[c] = (u32)v; pairB[c] = (u32)v; cscore[c] = 1.0f;
    }
  }
  if (t == 0) cnts[3] = totalC + totalL;
}

// ---------- outputs ----------
__global__ void k_newx(const float* __restrict__ x, const u32* __restrict__ pairA,
                       const u32* __restrict__ pairB, const float* __restrict__ cscore,
                       const u32* __restrict__ cnts, float* __restrict__ out, int N_)
{
  int j = blockIdx.x * blockDim.x + threadIdx.x;
  int total = N_ * (FDIM / 4);
  if (j >= total) return;
  u32 c = (u32)(j >> 5);
  int q = (j & 31) * 4;
  if (c >= cnts[3]) return;   // rows beyond num_clusters stay zero (memset)
  u32 a = pairA[c], bb = pairB[c];
  float cs = cscore[c];
  const float4 va = *(const float4*)(x + (size_t)a * FDIM + q);
  float4 o;
  if (a == bb) {
    o.x = __fmul_rn(va.x, cs); o.y = __fmul_rn(va.y, cs);
    o.z = __fmul_rn(va.z, cs); o.w = __fmul_rn(va.w, cs);
  } else {
    const float4 vb = *(const float4*)(x + (size_t)bb * FDIM + q);
    o.x = __fmul_rn(__fadd_rn(va.x, vb.x), cs);
    o.y = __fmul_rn(__fadd_rn(va.y, vb.y), cs);
    o.z = __fmul_rn(__fadd_rn(va.z, vb.z), cs);
    o.w = __fmul_rn(__fadd_rn(va.w, vb.w), cs);
  }
  *(float4*)(out + (size_t)c * FDIM + q) = o;
}

__global__ void k_newei(const int* __restrict__ ei, const int* __restrict__ cluster,
                        const u32* __restrict__ cnts, float* __restrict__ out, int N_, int E_)
{
  int e = blockIdx.x * blockDim.x + threadIdx.x;
  if (e >= E_) return;
  int c0 = cluster[ei[e]];
  int c1 = cluster[ei[E_ + e]];
  if (c0 == c1) { c0 = -1; c1 = -1; }
  size_t base = (size_t)N_ * FDIM;
  out[base + e] = (float)c0;
  out[base + E_ + e] = (float)c1;
  if (e == 0) out[base + 2 * (size_t)E_ + N_] = (float)cnts[3];  // num_clusters
}

extern "C" void kernel_launch(void* const* d_in, const int* in_sizes, int n_in,
                              void* d_out, int out_size, void* d_ws, size_t ws_size,
                              hipStream_t stream)
{
  const float* x    = (const float*)d_in[0];
  const int*   ei   = (const int*)d_in[1];
  const float* wsrc = (const float*)d_in[3];
  const float* wdst = (const float*)d_in[4];
  const float* b    = (const float*)d_in[5];
  const int N = in_sizes[0] / FDIM;
  const int E = in_sizes[1] / 2;

  // workspace layout (u32 words)
  u32* w = (u32*)d_ws;
  float* raw   = (float*)w;      w += E;
  float* score = (float*)w;      w += E;
  u32* kA = w;                   w += E;
  u32* vA = w;                   w += E;
  u32* kB = w;                   w += E;
  u32* vB = w;                   w += E;
  u32* m_enc  = w;               w += N;
  u32* counts = w;               w += N;
  u32* dstoff = w;               w += N;
  int* cluster = (int*)w;        w += N;
  u32* pairA = w;                w += N;
  u32* pairB = w;                w += N;
  float* cscore = (float*)w;     w += N;
  u32* cnts = w;                 w += 16;
  u32* hist = w;                 w += 64 * 256;   // radix histograms (nb*256 <= 64*256)

  // d_out doubles as scratch for match-phase arrays (dead before the output memset)
  u64* srcdstS = (u64*)d_out;                   // [0, 2E) u32 words
  u32* liveA  = (u32*)d_out + 2 * (size_t)E;
  u32* liveB  = (u32*)d_out + 3 * (size_t)E;
  u32* chosen = (u32*)d_out + 4 * (size_t)E;

  const int TB = 256;
  const int gridE = (E + TB - 1) / TB;
  const int gridN = (N + TB - 1) / TB;
  const int nb = (E + RCHUNK - 1) / RCHUNK;

  hipMemsetAsync(m_enc, 0, (size_t)N * 4, stream);
  hipMemsetAsync(counts, 0, (size_t)N * 4, stream);
  hipMemsetAsync(cnts, 0, 64, stream);

  k_raw<<<gridE, TB, 0, stream>>>(x, ei, wsrc, wdst, b, raw, m_enc, counts, N, E);
  k_scan_counts<<<1, WG, 0, stream>>>(counts, dstoff, N);

  // stable sort edges by dst: 2x 8-bit passes (keys < 2^15), A->B->A, result ids in vA
  k_key_dst<<<gridE, TB, 0, stream>>>(ei, kA, vA, E);
  {
    u32 *ka = kA, *va = vA, *kb = kB, *vb = vB;
    for (int p = 0; p < 2; ++p) {
      k_rhist<<<nb, RB, 0, stream>>>(ka, hist, E, nb, p * 8);
      k_rscan<<<1, WG, 0, stream>>>(hist, nb * 256);
      k_rscat<<<nb, RB, 0, stream>>>(ka, va, kb, vb, hist, E, nb, p * 8);
      u32* tk = ka; ka = kb; kb = tk; u32* tv = va; va = vb; vb = tv;
    }
  }

  k_scores<<<gridN, TB, 0, stream>>>(raw, m_enc, counts, dstoff, vA, score, N);

  // stable sort by descending score: 3x 8-bit passes (top byte of key constant:
  // score in [0.5,1.5] => key in [0x403FFFFF,0x40FFFFFF]), A->B->A->B, ids in vB
  k_key_score<<<gridE, TB, 0, stream>>>(score, kA, vA, E);
  {
    u32 *ka = kA, *va = vA, *kb = kB, *vb = vB;
    for (int p = 0; p < 3; ++p) {
      k_rhist<<<nb, RB, 0, stream>>>(ka, hist, E, nb, p * 8);
      k_rscan<<<1, WG, 0, stream>>>(hist, nb * 256);
      k_rscat<<<nb, RB, 0, stream>>>(ka, va, kb, vb, hist, E, nb, p * 8);
      u32* tk = ka; ka = kb; kb = tk; u32* tv = va; va = vb; vb = tv;
    }
  }

  k_match<<<1, WG, 0, stream>>>(ei, score, vB, srcdstS,
                                liveA, liveB, chosen,
                                cluster, pairA, pairB, cscore, cnts, N, E);

  hipMemsetAsync(d_out, 0, (size_t)out_size * 4, stream);  // new_x tail rows + new_batch = 0

  k_newx<<<(N * (FDIM / 4) + TB - 1) / TB, TB, 0, stream>>>(x, pairA, pairB, cscore, cnts, (float*)d_out, N);
  k_newei<<<gridE, TB, 0, stream>>>(ei, cluster, cnts, (float*)d_out, N, E);
}

// Round 3
// 956.322 us; speedup vs baseline: 9.1106x; 1.4838x over previous
//
#include <hip/hip_runtime.h>
#include <stdint.h>

typedef unsigned int u32;
typedef unsigned long long u64;
typedef unsigned short u16;
typedef unsigned char u8;

#define FDIM  128
#define NNODE 25000   // LDS sizing; N <= this
#define WG    1024
#define RB    256     // radix block threads
#define EPT   16      // radix elements per thread
#define RCHUNK (RB*EPT) // 4096 elements per radix block
// rank fits 18 bits (E <= 262144); round tag in upper 14 bits, decreasing per round
#define KBITS 18

// ---------- monotone float<->uint encoding (order-preserving) ----------
__device__ __forceinline__ u32 enc_f32(float f){
  u32 u = __float_as_uint(f);
  return (u & 0x80000000u) ? ~u : (u | 0x80000000u);
}
__device__ __forceinline__ float dec_f32(u32 u){
  u = (u & 0x80000000u) ? (u ^ 0x80000000u) : ~u;
  return __uint_as_float(u);
}

// ---------- XLA CPU GenerateVF32Exp replica (DO NOT TOUCH - validated r1) ----------
__device__ __forceinline__ float xla_expf(float x){
  x = fminf(x,  88.3762626647950f);
  x = fmaxf(x, -88.3762626647949f);
  float fx = floorf(fmaf(x, 1.44269504088896341f, 0.5f));
  float tmp = __fmul_rn(fx, 0.693359375f);
  float zz  = __fmul_rn(fx, -2.12194440e-4f);
  x = __fsub_rn(x, tmp);
  x = __fsub_rn(x, zz);
  float z2 = __fmul_rn(x, x);
  float y = fmaf(1.9875691500E-4f, x, 1.3981999507E-3f);
  y = fmaf(y, x, 8.3334519073E-3f);
  y = fmaf(y, x, 4.1665795894E-2f);
  y = fmaf(y, x, 1.6666665459E-1f);
  y = fmaf(y, x, 5.0000001201E-1f);
  y = fmaf(y, z2, x);
  y = __fadd_rn(y, 1.0f);
  int n = (int)fx;
  float p2n = __uint_as_float((u32)(n + 127) << 23);
  return __fmul_rn(y, p2n);
}

// ---------- raw edge scores + per-dst max/count (bit-identical to r1) ----------
__global__ __launch_bounds__(256) void k_raw(const float* __restrict__ x, const int* __restrict__ ei,
                      const float* __restrict__ wsrc, const float* __restrict__ wdst,
                      const float* __restrict__ b,
                      float* __restrict__ raw, u32* __restrict__ m_enc, u32* __restrict__ counts,
                      int N_, int E_)
{
  __shared__ float4 w4[64];
  int t = threadIdx.x;
  if (t < 32) w4[t] = ((const float4*)wsrc)[t];
  else if (t < 64) w4[t] = ((const float4*)wdst)[t - 32];
  __syncthreads();
  int e = blockIdx.x * blockDim.x + t;
  if (e >= E_) return;
  int s = ei[e], d = ei[E_ + e];
  const float4* xs = (const float4*)(x + (size_t)s * FDIM);
  const float4* xd = (const float4*)(x + (size_t)d * FDIM);
  float accs = 0.f, accd = 0.f;
  #pragma unroll 4
  for (int k = 0; k < 32; ++k) {
    float4 v = xs[k], w = w4[k];
    accs = __fadd_rn(accs, __fmul_rn(v.x, w.x));
    accs = __fadd_rn(accs, __fmul_rn(v.y, w.y));
    accs = __fadd_rn(accs, __fmul_rn(v.z, w.z));
    accs = __fadd_rn(accs, __fmul_rn(v.w, w.w));
  }
  #pragma unroll 4
  for (int k = 0; k < 32; ++k) {
    float4 v = xd[k], w = w4[k + 32];
    accd = __fadd_rn(accd, __fmul_rn(v.x, w.x));
    accd = __fadd_rn(accd, __fmul_rn(v.y, w.y));
    accd = __fadd_rn(accd, __fmul_rn(v.z, w.z));
    accd = __fadd_rn(accd, __fmul_rn(v.w, w.w));
  }
  float r = __fadd_rn(__fadd_rn(accs, accd), b[0]);
  raw[e] = r;
  atomicMax(&m_enc[d], enc_f32(r));
  atomicAdd(&counts[d], 1u);
}

// ---------- exclusive scan of per-dst counts (single block) ----------
__global__ __launch_bounds__(WG) void k_scan_counts(const u32* __restrict__ counts,
                                                    u32* __restrict__ dstoff, int N_)
{
  __shared__ u32 lds[WG];
  int t = threadIdx.x;
  int chunk = (N_ + WG - 1) / WG;
  int lo = t * chunk; if (lo > N_) lo = N_;
  int hi = lo + chunk; if (hi > N_) hi = N_;
  u32 s = 0;
  for (int v = lo; v < hi; ++v) s += counts[v];
  lds[t] = s; __syncthreads();
  for (int off = 1; off < WG; off <<= 1) {
    u32 a = (t >= off) ? lds[t - off] : 0u;
    __syncthreads();
    lds[t] += a;
    __syncthreads();
  }
  u32 run = lds[t] - s;
  for (int v = lo; v < hi; ++v) { dstoff[v] = run; run += counts[v]; }
}

// ---------- key builders ----------
__global__ void k_key_dst(const int* __restrict__ ei, u32* __restrict__ kA, u32* __restrict__ vA, int E_)
{
  int e = blockIdx.x * blockDim.x + threadIdx.x;
  if (e >= E_) return;
  kA[e] = (u32)ei[E_ + e];
  vA[e] = (u32)e;
}
__global__ void k_key_score(const float* __restrict__ score, u32* __restrict__ kA, u32* __restrict__ vA, int E_)
{
  int e = blockIdx.x * blockDim.x + threadIdx.x;
  if (e >= E_) return;
  kA[e] = ~enc_f32(score[e]);   // ascending => descending score; stable => edge id asc on ties
  vA[e] = (u32)e;
}

// ---------- multi-block stable LSD radix (8-bit digits) ----------
__global__ __launch_bounds__(RB) void k_rhist(const u32* __restrict__ key, u32* __restrict__ hist,
                                              int n, int nb, int shift)
{
  __shared__ u32 h[256];
  int t = threadIdx.x, b = blockIdx.x;
  h[t] = 0; __syncthreads();
  int lo = b * RCHUNK + t * EPT;
  int hi = lo + EPT; if (hi > n) hi = n;
  for (int i = lo; i < hi; ++i) atomicAdd(&h[(key[i] >> shift) & 255u], 1u);
  __syncthreads();
  hist[(size_t)t * nb + b] = h[t];   // digit-major layout
}

__global__ __launch_bounds__(WG) void k_rscan(u32* __restrict__ a, int m)
{
  __shared__ u32 lds[WG];
  int t = threadIdx.x;
  int chunk = (m + WG - 1) / WG;
  int lo = t * chunk; if (lo > m) lo = m;
  int hi = lo + chunk; if (hi > m) hi = m;
  u32 s = 0;
  for (int i = lo; i < hi; ++i) s += a[i];
  lds[t] = s; __syncthreads();
  for (int off = 1; off < WG; off <<= 1) {
    u32 v = (t >= off) ? lds[t - off] : 0u;
    __syncthreads();
    lds[t] += v;
    __syncthreads();
  }
  u32 run = lds[t] - s;
  for (int i = lo; i < hi; ++i) { u32 c = a[i]; a[i] = run; run += c; }
}

// stable scatter: per-(thread,digit) u16 local ranks + per-digit global base
__global__ __launch_bounds__(RB) void k_rscat(const u32* __restrict__ ka, const u32* __restrict__ va,
                                              u32* __restrict__ kb, u32* __restrict__ vb,
                                              const u32* __restrict__ base, int n, int nb, int shift)
{
  __shared__ u16 h[RB][258];     // [thread][digit], padded
  __shared__ u32 gbase[256];
  int t = threadIdx.x, b = blockIdx.x;
  for (int i = t; i < RB * 258 / 2; i += RB) ((u32*)h)[i] = 0u;
  __syncthreads();
  int lo = b * RCHUNK + t * EPT;
  int hi = lo + EPT; if (hi > n) hi = n;
  for (int i = lo; i < hi; ++i) { u32 d = (ka[i] >> shift) & 255u; h[t][d]++; }
  __syncthreads();
  { // thread t owns digit t: exclusive prefix over threads (local ranks <= 4096, fits u16)
    u32 run = 0;
    for (int q = 0; q < RB; ++q) { u16 c = h[q][t]; h[q][t] = (u16)run; run += c; }
    gbase[t] = base[(size_t)t * nb + b];
  }
  __syncthreads();
  for (int i = lo; i < hi; ++i) {
    u32 k = ka[i]; u32 d = (k >> shift) & 255u;
    u32 p = gbase[d] + (u32)h[t][d];
    h[t][d]++;
    kb[p] = k; vb[p] = va[i];
  }
}

// ---------- softmax scores: denom accumulated sequentially in edge-id order ----------
__global__ void k_scores(const float* __restrict__ raw, const u32* __restrict__ m_enc,
                         const u32* __restrict__ counts, const u32* __restrict__ dstoff,
                         const u32* __restrict__ ebydst, float* __restrict__ score, int N_)
{
  int v = blockIdx.x * blockDim.x + threadIdx.x;
  if (v >= N_) return;
  u32 c = counts[v];
  if (c == 0) return;
  u32 off = dstoff[v];
  float m = dec_f32(m_enc[v]);
  float denom = 0.f;
  for (u32 i = 0; i < c; ++i) {
    u32 e = ebydst[off + i];
    denom = __fadd_rn(denom, xla_expf(__fsub_rn(raw[e], m)));
  }
  for (u32 i = 0; i < c; ++i) {
    u32 e = ebydst[off + i];
    float z = xla_expf(__fsub_rn(raw[e], m));
    score[e] = __fadd_rn(__fdiv_rn(z, denom), 0.5f);
  }
}

// ---------- multi-block prep: rank-ordered live list + round-0 node_min ----------
__global__ void k_prep(const int* __restrict__ ei, const u32* __restrict__ sidx,
                       const float* __restrict__ score,
                       u64* __restrict__ live0, u32* __restrict__ pairByRank,
                       float* __restrict__ scoreByRank, u8* __restrict__ chosen,
                       u32* __restrict__ nmin_g, int E_)
{
  int k = blockIdx.x * blockDim.x + threadIdx.x;
  if (k >= E_) return;
  u32 e = sidx[k];
  u32 s = (u32)ei[e], d = (u32)ei[E_ + e];
  live0[k] = ((u64)(u32)k << 32) | ((u64)s << 16) | (u64)d;
  pairByRank[k] = (s << 16) | d;
  scoreByRank[k] = score[e];
  chosen[k] = 0;
  u32 val = (0x3FFFu << KBITS) | (u32)k;
  atomicMin(&nmin_g[s], val);
  atomicMin(&nmin_g[d], val);
}

// ---------- greedy matching: 2 passes/round, tagged node_min, ballot compaction ----------
__global__ __launch_bounds__(WG) void k_match(
    u64* liveA, u64* liveB, const u32* __restrict__ nmin_g,
    const u32* __restrict__ pairByRank, const float* __restrict__ scoreByRank,
    u8* __restrict__ chosen,
    int* __restrict__ cluster, u32* __restrict__ pairA, u32* __restrict__ pairB,
    float* __restrict__ cscore, u32* __restrict__ cnts, int N_, int E_)
{
  __shared__ u32 node_min[NNODE];
  __shared__ u8  matched[NNODE];
  __shared__ u32 lds[WG];
  __shared__ u32 s_nlive, s_next;
  const int t = threadIdx.x;
  const int lane = t & 63;

  for (int i = t; i < N_; i += WG) { node_min[i] = nmin_g[i]; matched[i] = 0; }
  if (t == 0) { s_nlive = (u32)E_; s_next = 0u; }
  __syncthreads();

  u64* LA = liveA; u64* LB = liveB;
  u32 r = 0;
  while (true) {
    u32 nl = s_nlive;
    if (nl == 0u || r > 16000u) break;
    const u32 tag  = (0x3FFFu - r) << KBITS;
    const u32 ntag = tag - (1u << KBITS);

    // P_choose: local-min edges are chosen; mark endpoints matched
    for (u32 i = (u32)t; i < nl; i += WG) {
      u64 v = LA[i];
      u32 k = (u32)(v >> 32);
      u32 s = ((u32)v) >> 16, d = (u32)v & 0xFFFFu;
      u32 myval = tag | k;
      if (node_min[s] == myval && node_min[d] == myval) {
        chosen[k] = 1; matched[s] = 1; matched[d] = 1;
      }
    }
    __syncthreads();

    // P_compact: survivors -> LB (ballot-aggregated), and post next-round mins
    for (u32 i0 = (u32)(t & ~63); i0 < nl; i0 += WG) {
      u32 i = i0 + (u32)lane;
      bool liveE = false; u64 v = 0;
      u32 s = 0, d = 0;
      if (i < nl) {
        v = LA[i];
        s = ((u32)v) >> 16; d = (u32)v & 0xFFFFu;
        liveE = (!matched[s] && !matched[d]);
      }
      u64 m = __ballot(liveE);
      if (m != 0ull) {
        int leader = __ffsll((long long)m) - 1;
        u32 baseIdx = 0;
        if (lane == leader) baseIdx = atomicAdd(&s_next, (u32)__popcll(m));
        baseIdx = (u32)__shfl((int)baseIdx, leader);
        if (liveE) {
          u32 pfx = (u32)__popcll(m & ((1ull << lane) - 1ull));
          LB[baseIdx + pfx] = v;
          u32 nval = ntag | (u32)(v >> 32);
          atomicMin(&node_min[s], nval);
          atomicMin(&node_min[d], nval);
        }
      }
    }
    __syncthreads();
    if (t == 0) { s_nlive = s_next; s_next = 0u; }
    { u64* tmp = LA; LA = LB; LB = tmp; }
    ++r;
    __syncthreads();
  }

  // ---- chosen-edge prefix scan (stable, contiguous chunks) -> pair-cluster ids ----
  int chunkE = (E_ + WG - 1) / WG;
  int lo = t * chunkE; if (lo > E_) lo = E_;
  int hi = lo + chunkE; if (hi > E_) hi = E_;
  u32 s = 0;
  for (int k = lo; k < hi; ++k) s += chosen[k];
  lds[t] = s; __syncthreads();
  for (int off = 1; off < WG; off <<= 1) {
    u32 a = (t >= off) ? lds[t - off] : 0u; __syncthreads();
    lds[t] += a; __syncthreads();
  }
  u32 totalC = lds[WG - 1];
  u32 run = lds[t] - s;
  for (int k = lo; k < hi; ++k) {
    if (chosen[k]) {
      u32 c = run++;
      u32 sd = pairByRank[k];
      u32 sv = sd >> 16, dv = sd & 0xFFFFu;
      cluster[sv] = (int)c; cluster[dv] = (int)c;
      pairA[c] = sv; pairB[c] = dv;
      cscore[c] = scoreByRank[k];
    }
  }
  __syncthreads();

  // ---- singleton ids: cnt + cumsum(unmatched) over node order ----
  int chunkN = (N_ + WG - 1) / WG;
  lo = t * chunkN; if (lo > N_) lo = N_;
  hi = lo + chunkN; if (hi > N_) hi = N_;
  s = 0;
  for (int v = lo; v < hi; ++v) s += (matched[v] ? 0u : 1u);
  lds[t] = s; __syncthreads();
  for (int off = 1; off < WG; off <<= 1) {
    u32 a = (t >= off) ? lds[t - off] : 0u; __syncthreads();
    lds[t] += a; __syncthreads();
  }
  u32 totalL = lds[WG - 1];
  run = lds[t] - s;
  for (int v = lo; v < hi; ++v) {
    if (!matched[v]) {
      u32 c = totalC + run++;
      cluster[v] = (int)c;
      pairA[c] = (u32)v; pairB[c] = (u32)v; cscore[c] = 1.0f;
    }
  }
  if (t == 0) cnts[3] = totalC + totalL;
}

// ---------- outputs ----------
__global__ void k_newx(const float* __restrict__ x, const u32* __restrict__ pairA,
                       const u32* __restrict__ pairB, const float* __restrict__ cscore,
                       const u32* __restrict__ cnts, float* __restrict__ out, int N_)
{
  int j = blockIdx.x * blockDim.x + threadIdx.x;
  int total = N_ * (FDIM / 4);
  if (j >= total) return;
  u32 c = (u32)(j >> 5);
  int q = (j & 31) * 4;
  if (c >= cnts[3]) return;   // rows beyond num_clusters stay zero (memset)
  u32 a = pairA[c], bb = pairB[c];
  float cs = cscore[c];
  const float4 va = *(const float4*)(x + (size_t)a * FDIM + q);
  float4 o;
  if (a == bb) {
    o.x = __fmul_rn(va.x, cs); o.y = __fmul_rn(va.y, cs);
    o.z = __fmul_rn(va.z, cs); o.w = __fmul_rn(va.w, cs);
  } else {
    const float4 vb = *(const float4*)(x + (size_t)bb * FDIM + q);
    o.x = __fmul_rn(__fadd_rn(va.x, vb.x), cs);
    o.y = __fmul_rn(__fadd_rn(va.y, vb.y), cs);
    o.z = __fmul_rn(__fadd_rn(va.z, vb.z), cs);
    o.w = __fmul_rn(__fadd_rn(va.w, vb.w), cs);
  }
  *(float4*)(out + (size_t)c * FDIM + q) = o;
}

__global__ void k_newei(const int* __restrict__ ei, const int* __restrict__ cluster,
                        const u32* __restrict__ cnts, float* __restrict__ out, int N_, int E_)
{
  int e = blockIdx.x * blockDim.x + threadIdx.x;
  if (e >= E_) return;
  int c0 = cluster[ei[e]];
  int c1 = cluster[ei[E_ + e]];
  if (c0 == c1) { c0 = -1; c1 = -1; }
  size_t base = (size_t)N_ * FDIM;
  out[base + e] = (float)c0;
  out[base + E_ + e] = (float)c1;
  if (e == 0) out[base + 2 * (size_t)E_ + N_] = (float)cnts[3];  // num_clusters
}

extern "C" void kernel_launch(void* const* d_in, const int* in_sizes, int n_in,
                              void* d_out, int out_size, void* d_ws, size_t ws_size,
                              hipStream_t stream)
{
  const float* x    = (const float*)d_in[0];
  const int*   ei   = (const int*)d_in[1];
  const float* wsrc = (const float*)d_in[3];
  const float* wdst = (const float*)d_in[4];
  const float* b    = (const float*)d_in[5];
  const int N = in_sizes[0] / FDIM;
  const int E = in_sizes[1] / 2;

  // workspace layout (u32 words)
  u32* w = (u32*)d_ws;
  float* raw   = (float*)w;      w += E;
  float* score = (float*)w;      w += E;
  u32* kA = w;                   w += E;
  u32* vA = w;                   w += E;
  u32* kB = w;                   w += E;
  u32* vB = w;                   w += E;
  u32* m_enc  = w;               w += N;
  u32* counts = w;               w += N;
  u32* dstoff = w;               w += N;
  int* cluster = (int*)w;        w += N;
  u32* pairA = w;                w += N;
  u32* pairB = w;                w += N;
  float* cscore = (float*)w;     w += N;
  u32* nmin_g = w;               w += N;
  u32* cnts = w;                 w += 16;
  u32* hist = w;                 w += 64 * 256;   // radix histograms (nb*256 <= 64*256)

  // d_out doubles as scratch for match-phase arrays (dead before the output memset)
  u64* liveA = (u64*)d_out;                                  // 2E words
  u64* liveB = (u64*)((u32*)d_out + 2 * (size_t)E);          // 2E words
  u32* pairByRank  = (u32*)d_out + 4 * (size_t)E;            // E words
  float* scoreByRank = (float*)((u32*)d_out + 5 * (size_t)E);// E words
  u8* chosen = (u8*)((u32*)d_out + 6 * (size_t)E);           // E bytes

  const int TB = 256;
  const int gridE = (E + TB - 1) / TB;
  const int gridN = (N + TB - 1) / TB;
  const int nb = (E + RCHUNK - 1) / RCHUNK;

  hipMemsetAsync(m_enc, 0, (size_t)N * 4, stream);
  hipMemsetAsync(counts, 0, (size_t)N * 4, stream);
  hipMemsetAsync(nmin_g, 0xFF, (size_t)N * 4, stream);
  hipMemsetAsync(cnts, 0, 64, stream);

  k_raw<<<gridE, TB, 0, stream>>>(x, ei, wsrc, wdst, b, raw, m_enc, counts, N, E);
  k_scan_counts<<<1, WG, 0, stream>>>(counts, dstoff, N);

  // stable sort edges by dst: 2x 8-bit passes (keys < 2^15), A->B->A, result ids in vA
  k_key_dst<<<gridE, TB, 0, stream>>>(ei, kA, vA, E);
  {
    u32 *ka = kA, *va = vA, *kb = kB, *vb = vB;
    for (int p = 0; p < 2; ++p) {
      k_rhist<<<nb, RB, 0, stream>>>(ka, hist, E, nb, p * 8);
      k_rscan<<<1, WG, 0, stream>>>(hist, nb * 256);
      k_rscat<<<nb, RB, 0, stream>>>(ka, va, kb, vb, hist, E, nb, p * 8);
      u32* tk = ka; ka = kb; kb = tk; u32* tv = va; va = vb; vb = tv;
    }
  }

  k_scores<<<gridN, TB, 0, stream>>>(raw, m_enc, counts, dstoff, vA, score, N);

  // stable sort by descending score: 3x 8-bit passes (top byte constant), ids end in vB
  k_key_score<<<gridE, TB, 0, stream>>>(score, kA, vA, E);
  {
    u32 *ka = kA, *va = vA, *kb = kB, *vb = vB;
    for (int p = 0; p < 3; ++p) {
      k_rhist<<<nb, RB, 0, stream>>>(ka, hist, E, nb, p * 8);
      k_rscan<<<1, WG, 0, stream>>>(hist, nb * 256);
      k_rscat<<<nb, RB, 0, stream>>>(ka, va, kb, vb, hist, E, nb, p * 8);
      u32* tk = ka; ka = kb; kb = tk; u32* tv = va; va = vb; vb = tv;
    }
  }

  // multi-block prep: rank-ordered live list, per-rank metadata, round-0 node mins
  k_prep<<<gridE, TB, 0, stream>>>(ei, vB, score, liveA, pairByRank, scoreByRank,
                                   chosen, nmin_g, E);

  k_match<<<1, WG, 0, stream>>>(liveA, liveB, nmin_g, pairByRank, scoreByRank, chosen,
                                cluster, pairA, pairB, cscore, cnts, N, E);

  hipMemsetAsync(d_out, 0, (size_t)out_size * 4, stream);  // new_x tail rows + new_batch = 0

  k_newx<<<(N * (FDIM / 4) + TB - 1) / TB, TB, 0, stream>>>(x, pairA, pairB, cscore, cnts, (float*)d_out, N);
  k_newei<<<gridE, TB, 0, stream>>>(ei, cluster, cnts, (float*)d_out, N, E);
}

// Round 4
// 830.513 us; speedup vs baseline: 10.4907x; 1.1515x over previous
//
#include <hip/hip_runtime.h>
#include <stdint.h>

typedef unsigned int u32;
typedef unsigned long long u64;
typedef unsigned short u16;
typedef unsigned char u8;

#define FDIM  128
#define NNODE 25000   // LDS sizing; N <= this
#define WG    1024
#define RB    256     // radix block threads
#define EPT   16      // radix elements per thread
#define RCHUNK (RB*EPT) // 4096 elements per radix block
// rank fits 18 bits (E <= 262144); round tag in upper 14 bits, decreasing per round
#define KBITS 18
#define TAG(r) (((0x3FFFu - (u32)(r)) << KBITS))

// ---------- monotone float<->uint encoding (order-preserving) ----------
__device__ __forceinline__ u32 enc_f32(float f){
  u32 u = __float_as_uint(f);
  return (u & 0x80000000u) ? ~u : (u | 0x80000000u);
}
__device__ __forceinline__ float dec_f32(u32 u){
  u = (u & 0x80000000u) ? (u ^ 0x80000000u) : ~u;
  return __uint_as_float(u);
}

// ---------- XLA CPU GenerateVF32Exp replica (DO NOT TOUCH - validated r1) ----------
__device__ __forceinline__ float xla_expf(float x){
  x = fminf(x,  88.3762626647950f);
  x = fmaxf(x, -88.3762626647949f);
  float fx = floorf(fmaf(x, 1.44269504088896341f, 0.5f));
  float tmp = __fmul_rn(fx, 0.693359375f);
  float zz  = __fmul_rn(fx, -2.12194440e-4f);
  x = __fsub_rn(x, tmp);
  x = __fsub_rn(x, zz);
  float z2 = __fmul_rn(x, x);
  float y = fmaf(1.9875691500E-4f, x, 1.3981999507E-3f);
  y = fmaf(y, x, 8.3334519073E-3f);
  y = fmaf(y, x, 4.1665795894E-2f);
  y = fmaf(y, x, 1.6666665459E-1f);
  y = fmaf(y, x, 5.0000001201E-1f);
  y = fmaf(y, z2, x);
  y = __fadd_rn(y, 1.0f);
  int n = (int)fx;
  float p2n = __uint_as_float((u32)(n + 127) << 23);
  return __fmul_rn(y, p2n);
}

// ---------- raw edge scores + per-dst max/count (bit-identical to r1) ----------
__global__ __launch_bounds__(256) void k_raw(const float* __restrict__ x, const int* __restrict__ ei,
                      const float* __restrict__ wsrc, const float* __restrict__ wdst,
                      const float* __restrict__ b,
                      float* __restrict__ raw, u32* __restrict__ m_enc, u32* __restrict__ counts,
                      int N_, int E_)
{
  __shared__ float4 w4[64];
  int t = threadIdx.x;
  if (t < 32) w4[t] = ((const float4*)wsrc)[t];
  else if (t < 64) w4[t] = ((const float4*)wdst)[t - 32];
  __syncthreads();
  int e = blockIdx.x * blockDim.x + t;
  if (e >= E_) return;
  int s = ei[e], d = ei[E_ + e];
  const float4* xs = (const float4*)(x + (size_t)s * FDIM);
  const float4* xd = (const float4*)(x + (size_t)d * FDIM);
  float accs = 0.f, accd = 0.f;
  #pragma unroll 4
  for (int k = 0; k < 32; ++k) {
    float4 v = xs[k], w = w4[k];
    accs = __fadd_rn(accs, __fmul_rn(v.x, w.x));
    accs = __fadd_rn(accs, __fmul_rn(v.y, w.y));
    accs = __fadd_rn(accs, __fmul_rn(v.z, w.z));
    accs = __fadd_rn(accs, __fmul_rn(v.w, w.w));
  }
  #pragma unroll 4
  for (int k = 0; k < 32; ++k) {
    float4 v = xd[k], w = w4[k + 32];
    accd = __fadd_rn(accd, __fmul_rn(v.x, w.x));
    accd = __fadd_rn(accd, __fmul_rn(v.y, w.y));
    accd = __fadd_rn(accd, __fmul_rn(v.z, w.z));
    accd = __fadd_rn(accd, __fmul_rn(v.w, w.w));
  }
  float r = __fadd_rn(__fadd_rn(accs, accd), b[0]);
  raw[e] = r;
  atomicMax(&m_enc[d], enc_f32(r));
  atomicAdd(&counts[d], 1u);
}

// ---------- exclusive scan of per-dst counts (single block) ----------
__global__ __launch_bounds__(WG) void k_scan_counts(const u32* __restrict__ counts,
                                                    u32* __restrict__ dstoff, int N_)
{
  __shared__ u32 lds[WG];
  int t = threadIdx.x;
  int chunk = (N_ + WG - 1) / WG;
  int lo = t * chunk; if (lo > N_) lo = N_;
  int hi = lo + chunk; if (hi > N_) hi = N_;
  u32 s = 0;
  for (int v = lo; v < hi; ++v) s += counts[v];
  lds[t] = s; __syncthreads();
  for (int off = 1; off < WG; off <<= 1) {
    u32 a = (t >= off) ? lds[t - off] : 0u;
    __syncthreads();
    lds[t] += a;
    __syncthreads();
  }
  u32 run = lds[t] - s;
  for (int v = lo; v < hi; ++v) { dstoff[v] = run; run += counts[v]; }
}

// ---------- key builders ----------
__global__ void k_key_dst(const int* __restrict__ ei, u32* __restrict__ kA, u32* __restrict__ vA, int E_)
{
  int e = blockIdx.x * blockDim.x + threadIdx.x;
  if (e >= E_) return;
  kA[e] = (u32)ei[E_ + e];
  vA[e] = (u32)e;
}
__global__ void k_key_score(const float* __restrict__ score, u32* __restrict__ kA, u32* __restrict__ vA, int E_)
{
  int e = blockIdx.x * blockDim.x + threadIdx.x;
  if (e >= E_) return;
  kA[e] = ~enc_f32(score[e]);   // ascending => descending score; stable => edge id asc on ties
  vA[e] = (u32)e;
}

// ---------- multi-block stable LSD radix (8-bit digits) ----------
__global__ __launch_bounds__(RB) void k_rhist(const u32* __restrict__ key, u32* __restrict__ hist,
                                              int n, int nb, int shift)
{
  __shared__ u32 h[256];
  int t = threadIdx.x, b = blockIdx.x;
  h[t] = 0; __syncthreads();
  int lo = b * RCHUNK + t * EPT;
  int hi = lo + EPT; if (hi > n) hi = n;
  for (int i = lo; i < hi; ++i) atomicAdd(&h[(key[i] >> shift) & 255u], 1u);
  __syncthreads();
  hist[(size_t)t * nb + b] = h[t];   // digit-major layout
}

__global__ __launch_bounds__(WG) void k_rscan(u32* __restrict__ a, int m)
{
  __shared__ u32 lds[WG];
  int t = threadIdx.x;
  int chunk = (m + WG - 1) / WG;
  int lo = t * chunk; if (lo > m) lo = m;
  int hi = lo + chunk; if (hi > m) hi = m;
  u32 s = 0;
  for (int i = lo; i < hi; ++i) s += a[i];
  lds[t] = s; __syncthreads();
  for (int off = 1; off < WG; off <<= 1) {
    u32 v = (t >= off) ? lds[t - off] : 0u;
    __syncthreads();
    lds[t] += v;
    __syncthreads();
  }
  u32 run = lds[t] - s;
  for (int i = lo; i < hi; ++i) { u32 c = a[i]; a[i] = run; run += c; }
}

// stable scatter: per-(thread,digit) u16 local ranks + per-digit global base
__global__ __launch_bounds__(RB) void k_rscat(const u32* __restrict__ ka, const u32* __restrict__ va,
                                              u32* __restrict__ kb, u32* __restrict__ vb,
                                              const u32* __restrict__ base, int n, int nb, int shift)
{
  __shared__ u16 h[RB][258];     // [thread][digit], padded
  __shared__ u32 gbase[256];
  int t = threadIdx.x, b = blockIdx.x;
  for (int i = t; i < RB * 258 / 2; i += RB) ((u32*)h)[i] = 0u;
  __syncthreads();
  int lo = b * RCHUNK + t * EPT;
  int hi = lo + EPT; if (hi > n) hi = n;
  for (int i = lo; i < hi; ++i) { u32 d = (ka[i] >> shift) & 255u; h[t][d]++; }
  __syncthreads();
  { // thread t owns digit t: exclusive prefix over threads (local ranks <= 4096, fits u16)
    u32 run = 0;
    for (int q = 0; q < RB; ++q) { u16 c = h[q][t]; h[q][t] = (u16)run; run += c; }
    gbase[t] = base[(size_t)t * nb + b];
  }
  __syncthreads();
  for (int i = lo; i < hi; ++i) {
    u32 k = ka[i]; u32 d = (k >> shift) & 255u;
    u32 p = gbase[d] + (u32)h[t][d];
    h[t][d]++;
    kb[p] = k; vb[p] = va[i];
  }
}

// ---------- softmax scores: denom accumulated sequentially in edge-id order ----------
__global__ void k_scores(const float* __restrict__ raw, const u32* __restrict__ m_enc,
                         const u32* __restrict__ counts, const u32* __restrict__ dstoff,
                         const u32* __restrict__ ebydst, float* __restrict__ score, int N_)
{
  int v = blockIdx.x * blockDim.x + threadIdx.x;
  if (v >= N_) return;
  u32 c = counts[v];
  if (c == 0) return;
  u32 off = dstoff[v];
  float m = dec_f32(m_enc[v]);
  float denom = 0.f;
  for (u32 i = 0; i < c; ++i) {
    u32 e = ebydst[off + i];
    denom = __fadd_rn(denom, xla_expf(__fsub_rn(raw[e], m)));
  }
  for (u32 i = 0; i < c; ++i) {
    u32 e = ebydst[off + i];
    float z = xla_expf(__fsub_rn(raw[e], m));
    score[e] = __fadd_rn(__fdiv_rn(z, denom), 0.5f);
  }
}

// ---------- multi-block prep: per-rank metadata + round-0 node mins ----------
__global__ void k_prep(const int* __restrict__ ei, const u32* __restrict__ sidx,
                       const float* __restrict__ score,
                       u32* __restrict__ pairByRank, float* __restrict__ scoreByRank,
                       u8* __restrict__ chosen, u32* __restrict__ nmin0, int E_)
{
  int k = blockIdx.x * blockDim.x + threadIdx.x;
  if (k >= E_) return;
  u32 e = sidx[k];
  u32 s = (u32)ei[e], d = (u32)ei[E_ + e];
  pairByRank[k] = (s << 16) | d;
  scoreByRank[k] = score[e];
  chosen[k] = 0;
  u32 val = TAG(0) | (u32)k;
  atomicMin(&nmin0[s], val);
  atomicMin(&nmin0[d], val);
}

// ---------- multi-block pre-round 0: choose + compact (fixpoint is order-free) ----------
__global__ void k_choose0(const u32* __restrict__ pairByRank, const u32* __restrict__ nmin0,
                          u8* __restrict__ chosen, u8* __restrict__ matched_g, int E_)
{
  int k = blockIdx.x * blockDim.x + threadIdx.x;
  if (k >= E_) return;
  u32 sd = pairByRank[k];
  u32 s = sd >> 16, d = sd & 0xFFFFu;
  u32 myval = TAG(0) | (u32)k;
  if (nmin0[s] == myval && nmin0[d] == myval) { chosen[k] = 1; matched_g[s] = 1; matched_g[d] = 1; }
}

__global__ void k_compact0(const u32* __restrict__ pairByRank, const u8* __restrict__ matched_g,
                           u64* __restrict__ liveOut, u32* __restrict__ nmin1,
                           u32* __restrict__ nlive, int E_)
{
  int k = blockIdx.x * blockDim.x + threadIdx.x;
  int lane = threadIdx.x & 63;
  bool liveE = false; u32 s = 0, d = 0;
  if (k < E_) {
    u32 sd = pairByRank[k];
    s = sd >> 16; d = sd & 0xFFFFu;
    liveE = (!matched_g[s] && !matched_g[d]);
  }
  u64 m = __ballot(liveE);
  if (m != 0ull) {
    int leader = __ffsll((long long)m) - 1;
    u32 base = 0;
    if (lane == leader) base = atomicAdd(nlive, (u32)__popcll(m));
    base = (u32)__shfl((int)base, leader);
    if (liveE) {
      u32 pfx = (u32)__popcll(m & ((1ull << lane) - 1ull));
      liveOut[base + pfx] = ((u64)(u32)k << 32) | ((u64)s << 16) | (u64)d;
      u32 nval = TAG(1) | (u32)k;
      atomicMin(&nmin1[s], nval);
      atomicMin(&nmin1[d], nval);
    }
  }
}

// ---------- multi-block pre-round 1 ----------
__global__ void k_choose1(const u64* __restrict__ liveIn, const u32* __restrict__ nlive,
                          const u32* __restrict__ nmin1,
                          u8* __restrict__ chosen, u8* __restrict__ matched_g)
{
  u32 i = blockIdx.x * blockDim.x + threadIdx.x;
  if (i >= *nlive) return;
  u64 v = liveIn[i];
  u32 k = (u32)(v >> 32), s = ((u32)v) >> 16, d = (u32)v & 0xFFFFu;
  u32 myval = TAG(1) | k;
  if (nmin1[s] == myval && nmin1[d] == myval) { chosen[k] = 1; matched_g[s] = 1; matched_g[d] = 1; }
}

__global__ void k_compact1(const u64* __restrict__ liveIn, const u32* __restrict__ nliveIn,
                           const u8* __restrict__ matched_g,
                           u64* __restrict__ liveOut, u32* __restrict__ nmin2,
                           u32* __restrict__ nliveOut)
{
  u32 i = blockIdx.x * blockDim.x + threadIdx.x;
  int lane = threadIdx.x & 63;
  bool liveE = false; u64 v = 0; u32 s = 0, d = 0;
  if (i < *nliveIn) {
    v = liveIn[i];
    s = ((u32)v) >> 16; d = (u32)v & 0xFFFFu;
    liveE = (!matched_g[s] && !matched_g[d]);
  }
  u64 m = __ballot(liveE);
  if (m != 0ull) {
    int leader = __ffsll((long long)m) - 1;
    u32 base = 0;
    if (lane == leader) base = atomicAdd(nliveOut, (u32)__popcll(m));
    base = (u32)__shfl((int)base, leader);
    if (liveE) {
      u32 pfx = (u32)__popcll(m & ((1ull << lane) - 1ull));
      liveOut[base + pfx] = v;
      u32 nval = TAG(2) | (u32)(v >> 32);
      atomicMin(&nmin2[s], nval);
      atomicMin(&nmin2[d], nval);
    }
  }
}

// ---------- single-block residual matching (rounds >= 2) + cluster ids ----------
// matched(v) encoded as node_min[v]==0 (0 is absorbing under atomicMin; tags only decrease)
__global__ __launch_bounds__(WG) void k_match(
    u64* liveA, u64* liveB, const u32* __restrict__ nmin2, const u8* __restrict__ matched_g,
    const u32* __restrict__ nlive2,
    const u32* __restrict__ pairByRank, const float* __restrict__ scoreByRank,
    u8* __restrict__ chosen,
    int* __restrict__ cluster, u32* __restrict__ pairA, u32* __restrict__ pairB,
    float* __restrict__ cscore, u32* __restrict__ cnts, int N_, int E_)
{
  __shared__ u32 node_min[NNODE];
  __shared__ u32 lds[WG];
  __shared__ u32 s_nlive, s_next;
  const int t = threadIdx.x;
  const int lane = t & 63;

  for (int i = t; i < N_; i += WG) node_min[i] = matched_g[i] ? 0u : nmin2[i];
  if (t == 0) { s_nlive = *nlive2; s_next = 0u; }
  __syncthreads();

  u64* LA = liveA; u64* LB = liveB;
  u32 r = 2;
  while (true) {
    u32 nl = s_nlive;
    if (nl == 0u || r > 16000u) break;
    const u32 tag  = TAG(r);
    const u32 ntag = TAG(r + 1);

    // P_choose: local-min edges are chosen; zero endpoints (matched)
    for (u32 i = (u32)t; i < nl; i += WG) {
      u64 v = LA[i];
      u32 k = (u32)(v >> 32);
      u32 s = ((u32)v) >> 16, d = (u32)v & 0xFFFFu;
      u32 myval = tag | k;
      if (node_min[s] == myval && node_min[d] == myval) {
        chosen[k] = 1; node_min[s] = 0u; node_min[d] = 0u;
      }
    }
    __syncthreads();

    // P_compact: survivors -> LB (ballot-aggregated), post next-round mins
    for (u32 i0 = (u32)(t & ~63); i0 < nl; i0 += WG) {
      u32 i = i0 + (u32)lane;
      bool liveE = false; u64 v = 0;
      u32 s = 0, d = 0;
      if (i < nl) {
        v = LA[i];
        s = ((u32)v) >> 16; d = (u32)v & 0xFFFFu;
        liveE = (node_min[s] != 0u && node_min[d] != 0u);
      }
      u64 m = __ballot(liveE);
      if (m != 0ull) {
        int leader = __ffsll((long long)m) - 1;
        u32 baseIdx = 0;
        if (lane == leader) baseIdx = atomicAdd(&s_next, (u32)__popcll(m));
        baseIdx = (u32)__shfl((int)baseIdx, leader);
        if (liveE) {
          u32 pfx = (u32)__popcll(m & ((1ull << lane) - 1ull));
          LB[baseIdx + pfx] = v;
          u32 nval = ntag | (u32)(v >> 32);
          atomicMin(&node_min[s], nval);
          atomicMin(&node_min[d], nval);
        }
      }
    }
    __syncthreads();
    if (t == 0) { s_nlive = s_next; s_next = 0u; }
    { u64* tmp = LA; LA = LB; LB = tmp; }
    ++r;
    __syncthreads();
  }

  // ---- chosen-edge prefix scan (stable, contiguous chunks) -> pair-cluster ids ----
  int chunkE = (E_ + WG - 1) / WG;
  int lo = t * chunkE; if (lo > E_) lo = E_;
  int hi = lo + chunkE; if (hi > E_) hi = E_;
  u32 s = 0;
  for (int k = lo; k < hi; ++k) s += chosen[k];
  lds[t] = s; __syncthreads();
  for (int off = 1; off < WG; off <<= 1) {
    u32 a = (t >= off) ? lds[t - off] : 0u; __syncthreads();
    lds[t] += a; __syncthreads();
  }
  u32 totalC = lds[WG - 1];
  u32 run = lds[t] - s;
  for (int k = lo; k < hi; ++k) {
    if (chosen[k]) {
      u32 c = run++;
      u32 sd = pairByRank[k];
      u32 sv = sd >> 16, dv = sd & 0xFFFFu;
      cluster[sv] = (int)c; cluster[dv] = (int)c;
      pairA[c] = sv; pairB[c] = dv;
      cscore[c] = scoreByRank[k];
    }
  }
  __syncthreads();

  // ---- singleton ids: cnt + cumsum(unmatched) over node order ----
  int chunkN = (N_ + WG - 1) / WG;
  lo = t * chunkN; if (lo > N_) lo = N_;
  hi = lo + chunkN; if (hi > N_) hi = N_;
  s = 0;
  for (int v = lo; v < hi; ++v) s += (node_min[v] == 0u ? 0u : 1u);
  lds[t] = s; __syncthreads();
  for (int off = 1; off < WG; off <<= 1) {
    u32 a = (t >= off) ? lds[t - off] : 0u; __syncthreads();
    lds[t] += a; __syncthreads();
  }
  u32 totalL = lds[WG - 1];
  run = lds[t] - s;
  for (int v = lo; v < hi; ++v) {
    if (node_min[v] != 0u) {
      u32 c = totalC + run++;
      cluster[v] = (int)c;
      pairA[c] = (u32)v; pairB[c] = (u32)v; cscore[c] = 1.0f;
    }
  }
  if (t == 0) cnts[3] = totalC + totalL;
}

// ---------- outputs ----------
__global__ void k_newx(const float* __restrict__ x, const u32* __restrict__ pairA,
                       const u32* __restrict__ pairB, const float* __restrict__ cscore,
                       const u32* __restrict__ cnts, float* __restrict__ out, int N_)
{
  int j = blockIdx.x * blockDim.x + threadIdx.x;
  int total = N_ * (FDIM / 4);
  if (j >= total) return;
  u32 c = (u32)(j >> 5);
  int q = (j & 31) * 4;
  if (c >= cnts[3]) return;   // rows beyond num_clusters stay zero (memset)
  u32 a = pairA[c], bb = pairB[c];
  float cs = cscore[c];
  const float4 va = *(const float4*)(x + (size_t)a * FDIM + q);
  float4 o;
  if (a == bb) {
    o.x = __fmul_rn(va.x, cs); o.y = __fmul_rn(va.y, cs);
    o.z = __fmul_rn(va.z, cs); o.w = __fmul_rn(va.w, cs);
  } else {
    const float4 vb = *(const float4*)(x + (size_t)bb * FDIM + q);
    o.x = __fmul_rn(__fadd_rn(va.x, vb.x), cs);
    o.y = __fmul_rn(__fadd_rn(va.y, vb.y), cs);
    o.z = __fmul_rn(__fadd_rn(va.z, vb.z), cs);
    o.w = __fmul_rn(__fadd_rn(va.w, vb.w), cs);
  }
  *(float4*)(out + (size_t)c * FDIM + q) = o;
}

__global__ void k_newei(const int* __restrict__ ei, const int* __restrict__ cluster,
                        const u32* __restrict__ cnts, float* __restrict__ out, int N_, int E_)
{
  int e = blockIdx.x * blockDim.x + threadIdx.x;
  if (e >= E_) return;
  int c0 = cluster[ei[e]];
  int c1 = cluster[ei[E_ + e]];
  if (c0 == c1) { c0 = -1; c1 = -1; }
  size_t base = (size_t)N_ * FDIM;
  out[base + e] = (float)c0;
  out[base + E_ + e] = (float)c1;
  if (e == 0) out[base + 2 * (size_t)E_ + N_] = (float)cnts[3];  // num_clusters
}

extern "C" void kernel_launch(void* const* d_in, const int* in_sizes, int n_in,
                              void* d_out, int out_size, void* d_ws, size_t ws_size,
                              hipStream_t stream)
{
  const float* x    = (const float*)d_in[0];
  const int*   ei   = (const int*)d_in[1];
  const float* wsrc = (const float*)d_in[3];
  const float* wdst = (const float*)d_in[4];
  const float* b    = (const float*)d_in[5];
  const int N = in_sizes[0] / FDIM;
  const int E = in_sizes[1] / 2;

  // workspace layout (u32 words)
  u32* w = (u32*)d_ws;
  float* raw   = (float*)w;      w += E;
  float* score = (float*)w;      w += E;
  u32* kA = w;                   w += E;
  u32* vA = w;                   w += E;
  u32* kB = w;                   w += E;
  u32* vB = w;                   w += E;
  u32* m_enc  = w;               w += N;
  u32* counts = w;               w += N;
  u32* dstoff = w;               w += N;
  int* cluster = (int*)w;        w += N;
  u32* pairA = w;                w += N;
  u32* pairB = w;                w += N;
  float* cscore = (float*)w;     w += N;
  u32* nmin0 = w;                w += N;
  u32* nmin1 = w;                w += N;
  u32* nmin2 = w;                w += N;
  u8*  matched_g = (u8*)w;       w += (N + 3) / 4;
  u32* cnts = w;                 w += 16;
  u32* hist = w;                 w += 64 * 256;   // radix histograms (nb*256 <= 64*256)

  // d_out doubles as scratch for match-phase arrays (dead before the output memset)
  u64* liveA = (u64*)d_out;                                  // 2E u32 words
  u64* liveB = (u64*)((u32*)d_out + 2 * (size_t)E);          // 2E words
  u32* pairByRank  = (u32*)d_out + 4 * (size_t)E;            // E words
  float* scoreByRank = (float*)((u32*)d_out + 5 * (size_t)E);// E words
  u8* chosen = (u8*)((u32*)d_out + 6 * (size_t)E);           // E bytes

  const int TB = 256;
  const int gridE = (E + TB - 1) / TB;
  const int gridN = (N + TB - 1) / TB;
  const int nb = (E + RCHUNK - 1) / RCHUNK;

  hipMemsetAsync(m_enc, 0, (size_t)N * 4, stream);
  hipMemsetAsync(counts, 0, (size_t)N * 4, stream);
  hipMemsetAsync(nmin0, 0xFF, (size_t)N * 4, stream);
  hipMemsetAsync(nmin1, 0xFF, (size_t)N * 4, stream);
  hipMemsetAsync(nmin2, 0xFF, (size_t)N * 4, stream);
  hipMemsetAsync(matched_g, 0, (size_t)N, stream);
  hipMemsetAsync(cnts, 0, 64, stream);

  k_raw<<<gridE, TB, 0, stream>>>(x, ei, wsrc, wdst, b, raw, m_enc, counts, N, E);
  k_scan_counts<<<1, WG, 0, stream>>>(counts, dstoff, N);

  // stable sort edges by dst: 2x 8-bit passes (keys < 2^15), A->B->A, result ids in vA
  k_key_dst<<<gridE, TB, 0, stream>>>(ei, kA, vA, E);
  {
    u32 *ka = kA, *va = vA, *kb = kB, *vb = vB;
    for (int p = 0; p < 2; ++p) {
      k_rhist<<<nb, RB, 0, stream>>>(ka, hist, E, nb, p * 8);
      k_rscan<<<1, WG, 0, stream>>>(hist, nb * 256);
      k_rscat<<<nb, RB, 0, stream>>>(ka, va, kb, vb, hist, E, nb, p * 8);
      u32* tk = ka; ka = kb; kb = tk; u32* tv = va; va = vb; vb = tv;
    }
  }

  k_scores<<<gridN, TB, 0, stream>>>(raw, m_enc, counts, dstoff, vA, score, N);

  // stable sort by descending score: 3x 8-bit passes (top byte constant), ids end in vB
  k_key_score<<<gridE, TB, 0, stream>>>(score, kA, vA, E);
  {
    u32 *ka = kA, *va = vA, *kb = kB, *vb = vB;
    for (int p = 0; p < 3; ++p) {
      k_rhist<<<nb, RB, 0, stream>>>(ka, hist, E, nb, p * 8);
      k_rscan<<<1, WG, 0, stream>>>(hist, nb * 256);
      k_rscat<<<nb, RB, 0, stream>>>(ka, va, kb, vb, hist, E, nb, p * 8);
      u32* tk = ka; ka = kb; kb = tk; u32* tv = va; va = vb; vb = tv;
    }
  }

  // prep: per-rank metadata + round-0 node mins (multi-block)
  k_prep<<<gridE, TB, 0, stream>>>(ei, vB, score, pairByRank, scoreByRank,
                                   chosen, nmin0, E);

  // pre-round 0 (multi-block): choose + compact -> liveB, nlive in cnts[0], mins in nmin1
  k_choose0<<<gridE, TB, 0, stream>>>(pairByRank, nmin0, chosen, matched_g, E);
  k_compact0<<<gridE, TB, 0, stream>>>(pairByRank, matched_g, liveB, nmin1, &cnts[0], E);

  // pre-round 1 (multi-block): choose + compact -> liveA, nlive in cnts[1], mins in nmin2
  k_choose1<<<gridE, TB, 0, stream>>>(liveB, &cnts[0], nmin1, chosen, matched_g);
  k_compact1<<<gridE, TB, 0, stream>>>(liveB, &cnts[0], matched_g, liveA, nmin2, &cnts[1]);

  // residual rounds (single block) + cluster-id assignment
  k_match<<<1, WG, 0, stream>>>(liveA, liveB, nmin2, matched_g, &cnts[1],
                                pairByRank, scoreByRank, chosen,
                                cluster, pairA, pairB, cscore, cnts, N, E);

  hipMemsetAsync(d_out, 0, (size_t)out_size * 4, stream);  // new_x tail rows + new_batch = 0

  k_newx<<<(N * (FDIM / 4) + TB - 1) / TB, TB, 0, stream>>>(x, pairA, pairB, cscore, cnts, (float*)d_out, N);
  k_newei<<<gridE, TB, 0, stream>>>(ei, cluster, cnts, (float*)d_out, N, E);
}

// Round 6
// 502.786 us; speedup vs baseline: 17.3288x; 1.6518x over previous
//
#include <hip/hip_runtime.h>
#include <stdint.h>

typedef unsigned int u32;
typedef unsigned long long u64;
typedef unsigned short u16;
typedef unsigned char u8;

#define FDIM  128
#define NNODE 25000   // LDS sizing; N <= this
#define WG    1024
#define RB    256     // radix block threads
#define EPT   16      // radix elements per thread
#define RCHUNK (RB*EPT) // 4096 elements per radix block
// rank fits 18 bits (E <= 262144); round tag in upper 14 bits, decreasing per round
#define KBITS 18
#define TAG(r) (((0x3FFFu - (u32)(r)) << KBITS))
#define PRROUNDS 4      // rounds 0..3 run multi-block; k_match starts at round 4
#define CB 256
#define CEPT 16
#define CCHUNK (CB*CEPT)

// ---------- monotone float<->uint encoding (order-preserving) ----------
__device__ __forceinline__ u32 enc_f32(float f){
  u32 u = __float_as_uint(f);
  return (u & 0x80000000u) ? ~u : (u | 0x80000000u);
}
__device__ __forceinline__ float dec_f32(u32 u){
  u = (u & 0x80000000u) ? (u ^ 0x80000000u) : ~u;
  return __uint_as_float(u);
}

// ---------- XLA CPU GenerateVF32Exp replica (DO NOT TOUCH - validated r1) ----------
__device__ __forceinline__ float xla_expf(float x){
  x = fminf(x,  88.3762626647950f);
  x = fmaxf(x, -88.3762626647949f);
  float fx = floorf(fmaf(x, 1.44269504088896341f, 0.5f));
  float tmp = __fmul_rn(fx, 0.693359375f);
  float zz  = __fmul_rn(fx, -2.12194440e-4f);
  x = __fsub_rn(x, tmp);
  x = __fsub_rn(x, zz);
  float z2 = __fmul_rn(x, x);
  float y = fmaf(1.9875691500E-4f, x, 1.3981999507E-3f);
  y = fmaf(y, x, 8.3334519073E-3f);
  y = fmaf(y, x, 4.1665795894E-2f);
  y = fmaf(y, x, 1.6666665459E-1f);
  y = fmaf(y, x, 5.0000001201E-1f);
  y = fmaf(y, z2, x);
  y = __fadd_rn(y, 1.0f);
  int n = (int)fx;
  float p2n = __uint_as_float((u32)(n + 127) << 23);
  return __fmul_rn(y, p2n);
}

// ---------- raw edge scores + per-dst max/count (bit-identical to r1) ----------
__global__ __launch_bounds__(256) void k_raw(const float* __restrict__ x, const int* __restrict__ ei,
                      const float* __restrict__ wsrc, const float* __restrict__ wdst,
                      const float* __restrict__ b,
                      float* __restrict__ raw, u32* __restrict__ m_enc, u32* __restrict__ counts,
                      int N_, int E_)
{
  __shared__ float4 w4[64];
  int t = threadIdx.x;
  if (t < 32) w4[t] = ((const float4*)wsrc)[t];
  else if (t < 64) w4[t] = ((const float4*)wdst)[t - 32];
  __syncthreads();
  int e = blockIdx.x * blockDim.x + t;
  if (e >= E_) return;
  int s = ei[e], d = ei[E_ + e];
  const float4* xs = (const float4*)(x + (size_t)s * FDIM);
  const float4* xd = (const float4*)(x + (size_t)d * FDIM);
  float accs = 0.f, accd = 0.f;
  #pragma unroll 4
  for (int k = 0; k < 32; ++k) {
    float4 v = xs[k], w = w4[k];
    accs = __fadd_rn(accs, __fmul_rn(v.x, w.x));
    accs = __fadd_rn(accs, __fmul_rn(v.y, w.y));
    accs = __fadd_rn(accs, __fmul_rn(v.z, w.z));
    accs = __fadd_rn(accs, __fmul_rn(v.w, w.w));
  }
  #pragma unroll 4
  for (int k = 0; k < 32; ++k) {
    float4 v = xd[k], w = w4[k + 32];
    accd = __fadd_rn(accd, __fmul_rn(v.x, w.x));
    accd = __fadd_rn(accd, __fmul_rn(v.y, w.y));
    accd = __fadd_rn(accd, __fmul_rn(v.z, w.z));
    accd = __fadd_rn(accd, __fmul_rn(v.w, w.w));
  }
  float r = __fadd_rn(__fadd_rn(accs, accd), b[0]);
  raw[e] = r;
  atomicMax(&m_enc[d], enc_f32(r));
  atomicAdd(&counts[d], 1u);
}

// ---------- exclusive scan of per-dst counts (single block) ----------
__global__ __launch_bounds__(WG) void k_scan_counts(const u32* __restrict__ counts,
                                                    u32* __restrict__ dstoff, int N_)
{
  __shared__ u32 lds[WG];
  int t = threadIdx.x;
  int chunk = (N_ + WG - 1) / WG;
  int lo = t * chunk; if (lo > N_) lo = N_;
  int hi = lo + chunk; if (hi > N_) hi = N_;
  u32 s = 0;
  for (int v = lo; v < hi; ++v) s += counts[v];
  lds[t] = s; __syncthreads();
  for (int off = 1; off < WG; off <<= 1) {
    u32 a = (t >= off) ? lds[t - off] : 0u;
    __syncthreads();
    lds[t] += a;
    __syncthreads();
  }
  u32 run = lds[t] - s;
  for (int v = lo; v < hi; ++v) { dstoff[v] = run; run += counts[v]; }
}

// ---------- key builders ----------
__global__ void k_key_dst(const int* __restrict__ ei, u32* __restrict__ kA, u32* __restrict__ vA, int E_)
{
  int e = blockIdx.x * blockDim.x + threadIdx.x;
  if (e >= E_) return;
  kA[e] = (u32)ei[E_ + e];
  vA[e] = (u32)e;
}
__global__ void k_key_score(const float* __restrict__ score, u32* __restrict__ kA, u32* __restrict__ vA, int E_)
{
  int e = blockIdx.x * blockDim.x + threadIdx.x;
  if (e >= E_) return;
  kA[e] = ~enc_f32(score[e]);   // ascending => descending score; stable => edge id asc on ties
  vA[e] = (u32)e;
}

// ---------- multi-block stable LSD radix (8-bit digits) ----------
__global__ __launch_bounds__(RB) void k_rhist(const u32* __restrict__ key, u32* __restrict__ hist,
                                              int n, int nb, int shift)
{
  __shared__ u32 h[256];
  int t = threadIdx.x, b = blockIdx.x;
  h[t] = 0; __syncthreads();
  int lo = b * RCHUNK + t * EPT;
  int hi = lo + EPT; if (hi > n) hi = n;
  for (int i = lo; i < hi; ++i) atomicAdd(&h[(key[i] >> shift) & 255u], 1u);
  __syncthreads();
  hist[(size_t)t * nb + b] = h[t];   // digit-major layout
}

__global__ __launch_bounds__(WG) void k_rscan(u32* __restrict__ a, int m)
{
  __shared__ u32 lds[WG];
  int t = threadIdx.x;
  int chunk = (m + WG - 1) / WG;
  int lo = t * chunk; if (lo > m) lo = m;
  int hi = lo + chunk; if (hi > m) hi = m;
  u32 s = 0;
  for (int i = lo; i < hi; ++i) s += a[i];
  lds[t] = s; __syncthreads();
  for (int off = 1; off < WG; off <<= 1) {
    u32 v = (t >= off) ? lds[t - off] : 0u;
    __syncthreads();
    lds[t] += v;
    __syncthreads();
  }
  u32 run = lds[t] - s;
  for (int i = lo; i < hi; ++i) { u32 c = a[i]; a[i] = run; run += c; }
}

// stable scatter: per-(thread,digit) u16 local ranks + per-digit global base
__global__ __launch_bounds__(RB) void k_rscat(const u32* __restrict__ ka, const u32* __restrict__ va,
                                              u32* __restrict__ kb, u32* __restrict__ vb,
                                              const u32* __restrict__ base, int n, int nb, int shift)
{
  __shared__ u16 h[RB][258];     // [thread][digit], padded
  __shared__ u32 gbase[256];
  int t = threadIdx.x, b = blockIdx.x;
  for (int i = t; i < RB * 258 / 2; i += RB) ((u32*)h)[i] = 0u;
  __syncthreads();
  int lo = b * RCHUNK + t * EPT;
  int hi = lo + EPT; if (hi > n) hi = n;
  for (int i = lo; i < hi; ++i) { u32 d = (ka[i] >> shift) & 255u; h[t][d]++; }
  __syncthreads();
  { // thread t owns digit t: exclusive prefix over threads (local ranks <= 4096, fits u16)
    u32 run = 0;
    for (int q = 0; q < RB; ++q) { u16 c = h[q][t]; h[q][t] = (u16)run; run += c; }
    gbase[t] = base[(size_t)t * nb + b];
  }
  __syncthreads();
  for (int i = lo; i < hi; ++i) {
    u32 k = ka[i]; u32 d = (k >> shift) & 255u;
    u32 p = gbase[d] + (u32)h[t][d];
    h[t][d]++;
    kb[p] = k; vb[p] = va[i];
  }
}

// ---------- softmax scores: denom accumulated sequentially in edge-id order ----------
__global__ void k_scores(const float* __restrict__ raw, const u32* __restrict__ m_enc,
                         const u32* __restrict__ counts, const u32* __restrict__ dstoff,
                         const u32* __restrict__ ebydst, float* __restrict__ score, int N_)
{
  int v = blockIdx.x * blockDim.x + threadIdx.x;
  if (v >= N_) return;
  u32 c = counts[v];
  if (c == 0) return;
  u32 off = dstoff[v];
  float m = dec_f32(m_enc[v]);
  float denom = 0.f;
  for (u32 i = 0; i < c; ++i) {
    u32 e = ebydst[off + i];
    denom = __fadd_rn(denom, xla_expf(__fsub_rn(raw[e], m)));
  }
  for (u32 i = 0; i < c; ++i) {
    u32 e = ebydst[off + i];
    float z = xla_expf(__fsub_rn(raw[e], m));
    score[e] = __fadd_rn(__fdiv_rn(z, denom), 0.5f);
  }
}

// ---------- multi-block prep: per-rank metadata + round-0 node mins ----------
__global__ void k_prep(const int* __restrict__ ei, const u32* __restrict__ sidx,
                       const float* __restrict__ score,
                       u32* __restrict__ pairByRank, float* __restrict__ scoreByRank,
                       u8* __restrict__ chosen, u32* __restrict__ nmin, int E_)
{
  int k = blockIdx.x * blockDim.x + threadIdx.x;
  if (k >= E_) return;
  u32 e = sidx[k];
  u32 s = (u32)ei[e], d = (u32)ei[E_ + e];
  pairByRank[k] = (s << 16) | d;
  scoreByRank[k] = score[e];
  chosen[k] = 0;
  u32 val = TAG(0) | (u32)k;
  atomicMin(&nmin[s], val);
  atomicMin(&nmin[d], val);
}

// ---------- pre-round 0 (implicit live list = all ranks) ----------
__global__ void k_choose0(const u32* __restrict__ pairByRank, const u32* __restrict__ nmin,
                          u8* __restrict__ chosen, u8* __restrict__ matched_g, int E_)
{
  int k = blockIdx.x * blockDim.x + threadIdx.x;
  if (k >= E_) return;
  u32 sd = pairByRank[k];
  u32 s = sd >> 16, d = sd & 0xFFFFu;
  u32 myval = TAG(0) | (u32)k;
  if (nmin[s] == myval && nmin[d] == myval) { chosen[k] = 1; matched_g[s] = 1; matched_g[d] = 1; }
}

__global__ void k_compact0(const u32* __restrict__ pairByRank, const u8* __restrict__ matched_g,
                           u64* __restrict__ liveOut, u32* __restrict__ nmin,
                           u32* __restrict__ nlive, int E_)
{
  int k = blockIdx.x * blockDim.x + threadIdx.x;
  int lane = threadIdx.x & 63;
  bool liveE = false; u32 s = 0, d = 0;
  if (k < E_) {
    u32 sd = pairByRank[k];
    s = sd >> 16; d = sd & 0xFFFFu;
    liveE = (!matched_g[s] && !matched_g[d]);
  }
  u64 m = __ballot(liveE);
  if (m != 0ull) {
    int leader = __ffsll((long long)m) - 1;
    u32 base = 0;
    if (lane == leader) base = atomicAdd(nlive, (u32)__popcll(m));
    base = (u32)__shfl((int)base, leader);
    if (liveE) {
      u32 pfx = (u32)__popcll(m & ((1ull << lane) - 1ull));
      liveOut[base + pfx] = ((u64)(u32)k << 32) | ((u64)s << 16) | (u64)d;
      u32 nval = TAG(1) | (u32)k;
      atomicMin(&nmin[s], nval);
      atomicMin(&nmin[d], nval);
    }
  }
}

// ---------- generic pre-round r >= 1 (single nmin array; tags strictly decrease,
//            kernels stream-serialized so round-r equality check completes before
//            round-r+1 mins are posted) ----------
__global__ void k_chooseR(const u64* __restrict__ liveIn, const u32* __restrict__ nliveIn,
                          const u32* __restrict__ nmin,
                          u8* __restrict__ chosen, u8* __restrict__ matched_g, u32 rtag)
{
  u32 i = blockIdx.x * blockDim.x + threadIdx.x;
  if (i >= *nliveIn) return;
  u64 v = liveIn[i];
  u32 k = (u32)(v >> 32), s = ((u32)v) >> 16, d = (u32)v & 0xFFFFu;
  u32 myval = rtag | k;
  if (nmin[s] == myval && nmin[d] == myval) { chosen[k] = 1; matched_g[s] = 1; matched_g[d] = 1; }
}

__global__ void k_compactR(const u64* __restrict__ liveIn, const u32* __restrict__ nliveIn,
                           const u8* __restrict__ matched_g,
                           u64* __restrict__ liveOut, u32* __restrict__ nmin,
                           u32* __restrict__ nliveOut, u32 ntag)
{
  u32 i = blockIdx.x * blockDim.x + threadIdx.x;
  int lane = threadIdx.x & 63;
  bool liveE = false; u64 v = 0; u32 s = 0, d = 0;
  if (i < *nliveIn) {
    v = liveIn[i];
    s = ((u32)v) >> 16; d = (u32)v & 0xFFFFu;
    liveE = (!matched_g[s] && !matched_g[d]);
  }
  u64 m = __ballot(liveE);
  if (m != 0ull) {
    int leader = __ffsll((long long)m) - 1;
    u32 base = 0;
    if (lane == leader) base = atomicAdd(nliveOut, (u32)__popcll(m));
    base = (u32)__shfl((int)base, leader);
    if (liveE) {
      u32 pfx = (u32)__popcll(m & ((1ull << lane) - 1ull));
      liveOut[base + pfx] = v;
      u32 nval = ntag | (u32)(v >> 32);
      atomicMin(&nmin[s], nval);
      atomicMin(&nmin[d], nval);
    }
  }
}

// ---------- single-block residual fixpoint (rounds >= PRROUNDS) ----------
// matched(v) encoded as node_min[v]==0 (absorbing under atomicMin; tags only decrease).
// Writes chosen[] (global) and final matched flags back to matched_g.
__global__ __launch_bounds__(WG) void k_match(
    u64* liveA, u64* liveB, const u32* __restrict__ nmin_g, u8* __restrict__ matched_g,
    const u32* __restrict__ nliveIn, u8* __restrict__ chosen, int N_)
{
  __shared__ u32 node_min[NNODE];
  __shared__ u32 s_nlive, s_next;
  const int t = threadIdx.x;
  const int lane = t & 63;

  for (int i = t; i < N_; i += WG) node_min[i] = matched_g[i] ? 0u : nmin_g[i];
  if (t == 0) { s_nlive = *nliveIn; s_next = 0u; }
  __syncthreads();

  u64* LA = liveA; u64* LB = liveB;
  u32 r = PRROUNDS;
  while (true) {
    u32 nl = s_nlive;
    if (nl == 0u || r > 16000u) break;
    const u32 tag  = TAG(r);
    const u32 ntag = TAG(r + 1);

    // P_choose: local-min edges are chosen; zero endpoints (matched)
    for (u32 i = (u32)t; i < nl; i += WG) {
      u64 v = LA[i];
      u32 k = (u32)(v >> 32);
      u32 s = ((u32)v) >> 16, d = (u32)v & 0xFFFFu;
      u32 myval = tag | k;
      if (node_min[s] == myval && node_min[d] == myval) {
        chosen[k] = 1; node_min[s] = 0u; node_min[d] = 0u;
      }
    }
    __syncthreads();

    // P_compact: survivors -> LB (ballot-aggregated), post next-round mins
    for (u32 i0 = (u32)(t & ~63); i0 < nl; i0 += WG) {
      u32 i = i0 + (u32)lane;
      bool liveE = false; u64 v = 0;
      u32 s = 0, d = 0;
      if (i < nl) {
        v = LA[i];
        s = ((u32)v) >> 16; d = (u32)v & 0xFFFFu;
        liveE = (node_min[s] != 0u && node_min[d] != 0u);
      }
      u64 m = __ballot(liveE);
      if (m != 0ull) {
        int leader = __ffsll((long long)m) - 1;
        u32 baseIdx = 0;
        if (lane == leader) baseIdx = atomicAdd(&s_next, (u32)__popcll(m));
        baseIdx = (u32)__shfl((int)baseIdx, leader);
        if (liveE) {
          u32 pfx = (u32)__popcll(m & ((1ull << lane) - 1ull));
          LB[baseIdx + pfx] = v;
          u32 nval = ntag | (u32)(v >> 32);
          atomicMin(&node_min[s], nval);
          atomicMin(&node_min[d], nval);
        }
      }
    }
    __syncthreads();
    if (t == 0) { s_nlive = s_next; s_next = 0u; }
    { u64* tmp = LA; LA = LB; LB = tmp; }
    ++r;
    __syncthreads();
  }

  for (int i = t; i < N_; i += WG) matched_g[i] = (node_min[i] == 0u) ? 1 : 0;
}

// ---------- multi-block cluster-id assignment ----------
__global__ __launch_bounds__(CB) void k_csum(const u8* __restrict__ chosen, u32* __restrict__ csum, int E_)
{
  __shared__ u32 sh[CB];
  int t = threadIdx.x, b = blockIdx.x;
  int lo = b * CCHUNK + t * CEPT;
  int hi = lo + CEPT; if (hi > E_) hi = E_;
  u32 c = 0;
  for (int i = lo; i < hi; ++i) c += chosen[i];
  sh[t] = c; __syncthreads();
  for (int off = CB / 2; off > 0; off >>= 1) { if (t < off) sh[t] += sh[t + off]; __syncthreads(); }
  if (t == 0) csum[b] = sh[0];
}

__global__ __launch_bounds__(CB) void k_nsum(const u8* __restrict__ matched, u32* __restrict__ nsum, int N_)
{
  __shared__ u32 sh[CB];
  int t = threadIdx.x, b = blockIdx.x;
  int lo = b * CCHUNK + t * CEPT;
  int hi = lo + CEPT; if (hi > N_) hi = N_;
  u32 c = 0;
  for (int i = lo; i < hi; ++i) c += (matched[i] ? 0u : 1u);
  sh[t] = c; __syncthreads();
  for (int off = CB / 2; off > 0; off >>= 1) { if (t < off) sh[t] += sh[t + off]; __syncthreads(); }
  if (t == 0) nsum[b] = sh[0];
}

__global__ void k_scan2(u32* __restrict__ csum, int nbc, u32* __restrict__ nsum, int nbn,
                        u32* __restrict__ cnts)
{
  if (threadIdx.x == 0) {
    u32 run = 0;
    for (int i = 0; i < nbc; ++i) { u32 v = csum[i]; csum[i] = run; run += v; }
    cnts[4] = run;                       // totalC (pair clusters)
    u32 run2 = 0;
    for (int i = 0; i < nbn; ++i) { u32 v = nsum[i]; nsum[i] = run2; run2 += v; }
    cnts[3] = run + run2;                // num_clusters
  }
}

__global__ __launch_bounds__(CB) void k_cassign(const u8* __restrict__ chosen, const u32* __restrict__ csum,
    const u32* __restrict__ pairByRank, const float* __restrict__ scoreByRank,
    int* __restrict__ cluster, u32* __restrict__ pairA, u32* __restrict__ pairB,
    float* __restrict__ cscore, int E_)
{
  __shared__ u32 sh[CB];
  int t = threadIdx.x, b = blockIdx.x;
  int lo = b * CCHUNK + t * CEPT;
  int hi = lo + CEPT; if (hi > E_) hi = E_;
  u32 c = 0;
  for (int i = lo; i < hi; ++i) c += chosen[i];
  u32 mine = c;
  sh[t] = c; __syncthreads();
  for (int off = 1; off < CB; off <<= 1) {
    u32 a = (t >= off) ? sh[t - off] : 0u; __syncthreads();
    sh[t] += a; __syncthreads();
  }
  u32 run = csum[b] + sh[t] - mine;
  for (int i = lo; i < hi; ++i) {
    if (chosen[i]) {
      u32 cc = run++;
      u32 sd = pairByRank[i];
      u32 sv = sd >> 16, dv = sd & 0xFFFFu;
      cluster[sv] = (int)cc; cluster[dv] = (int)cc;
      pairA[cc] = sv; pairB[cc] = dv; cscore[cc] = scoreByRank[i];
    }
  }
}

__global__ __launch_bounds__(CB) void k_nassign(const u8* __restrict__ matched, const u32* __restrict__ nsum,
    const u32* __restrict__ cnts,
    int* __restrict__ cluster, u32* __restrict__ pairA, u32* __restrict__ pairB,
    float* __restrict__ cscore, int N_)
{
  __shared__ u32 sh[CB];
  int t = threadIdx.x, b = blockIdx.x;
  int lo = b * CCHUNK + t * CEPT;
  int hi = lo + CEPT; if (hi > N_) hi = N_;
  u32 c = 0;
  for (int i = lo; i < hi; ++i) c += (matched[i] ? 0u : 1u);
  u32 mine = c;
  sh[t] = c; __syncthreads();
  for (int off = 1; off < CB; off <<= 1) {
    u32 a = (t >= off) ? sh[t - off] : 0u; __syncthreads();
    sh[t] += a; __syncthreads();
  }
  u32 run = cnts[4] + nsum[b] + sh[t] - mine;
  for (int v = lo; v < hi; ++v) {
    if (!matched[v]) {
      u32 cc = run++;
      cluster[v] = (int)cc;
      pairA[cc] = (u32)v; pairB[cc] = (u32)v; cscore[cc] = 1.0f;
    }
  }
}

// ---------- outputs ----------
__global__ void k_newx(const float* __restrict__ x, const u32* __restrict__ pairA,
                       const u32* __restrict__ pairB, const float* __restrict__ cscore,
                       const u32* __restrict__ cnts, float* __restrict__ out, int N_)
{
  int j = blockIdx.x * blockDim.x + threadIdx.x;
  int total = N_ * (FDIM / 4);
  if (j >= total) return;
  u32 c = (u32)(j >> 5);
  int q = (j & 31) * 4;
  if (c >= cnts[3]) return;   // rows beyond num_clusters stay zero (memset)
  u32 a = pairA[c], bb = pairB[c];
  float cs = cscore[c];
  const float4 va = *(const float4*)(x + (size_t)a * FDIM + q);
  float4 o;
  if (a == bb) {
    o.x = __fmul_rn(va.x, cs); o.y = __fmul_rn(va.y, cs);
    o.z = __fmul_rn(va.z, cs); o.w = __fmul_rn(va.w, cs);
  } else {
    const float4 vb = *(const float4*)(x + (size_t)bb * FDIM + q);
    o.x = __fmul_rn(__fadd_rn(va.x, vb.x), cs);
    o.y = __fmul_rn(__fadd_rn(va.y, vb.y), cs);
    o.z = __fmul_rn(__fadd_rn(va.z, vb.z), cs);
    o.w = __fmul_rn(__fadd_rn(va.w, vb.w), cs);
  }
  *(float4*)(out + (size_t)c * FDIM + q) = o;
}

__global__ void k_newei(const int* __restrict__ ei, const int* __restrict__ cluster,
                        const u32* __restrict__ cnts, float* __restrict__ out, int N_, int E_)
{
  int e = blockIdx.x * blockDim.x + threadIdx.x;
  if (e >= E_) return;
  int c0 = cluster[ei[e]];
  int c1 = cluster[ei[E_ + e]];
  if (c0 == c1) { c0 = -1; c1 = -1; }
  size_t base = (size_t)N_ * FDIM;
  out[base + e] = (float)c0;
  out[base + E_ + e] = (float)c1;
  if (e == 0) out[base + 2 * (size_t)E_ + N_] = (float)cnts[3];  // num_clusters
}

extern "C" void kernel_launch(void* const* d_in, const int* in_sizes, int n_in,
                              void* d_out, int out_size, void* d_ws, size_t ws_size,
                              hipStream_t stream)
{
  const float* x    = (const float*)d_in[0];
  const int*   ei   = (const int*)d_in[1];
  const float* wsrc = (const float*)d_in[3];
  const float* wdst = (const float*)d_in[4];
  const float* b    = (const float*)d_in[5];
  const int N = in_sizes[0] / FDIM;
  const int E = in_sizes[1] / 2;

  // workspace layout (u32 words)
  u32* w = (u32*)d_ws;
  float* raw   = (float*)w;      w += E;
  float* score = (float*)w;      w += E;
  u32* kA = w;                   w += E;
  u32* vA = w;                   w += E;
  u32* kB = w;                   w += E;
  u32* vB = w;                   w += E;
  u32* m_enc  = w;               w += N;
  u32* counts = w;               w += N;
  u32* dstoff = w;               w += N;
  int* cluster = (int*)w;        w += N;
  u32* pairA = w;                w += N;
  u32* pairB = w;                w += N;
  float* cscore = (float*)w;     w += N;
  u32* nmin = w;                 w += N;
  u8*  matched_g = (u8*)w;       w += (N + 3) / 4;
  u32* cnts = w;                 w += 16;
  u32* csum = w;                 w += 64;
  u32* nsum = w;                 w += 16;
  u32* hist = w;                 w += 64 * 256;   // radix histograms (nb*256 <= 64*256)

  // d_out doubles as scratch for match-phase arrays (dead before the output memset)
  u64* liveA = (u64*)d_out;                                  // 2E u32 words
  u64* liveB = (u64*)((u32*)d_out + 2 * (size_t)E);          // 2E words
  u32* pairByRank  = (u32*)d_out + 4 * (size_t)E;            // E words
  float* scoreByRank = (float*)((u32*)d_out + 5 * (size_t)E);// E words
  u8* chosen = (u8*)((u32*)d_out + 6 * (size_t)E);           // E bytes

  const int TB = 256;
  const int gridE = (E + TB - 1) / TB;
  const int gridN = (N + TB - 1) / TB;
  const int nb = (E + RCHUNK - 1) / RCHUNK;
  const int nbc = (E + CCHUNK - 1) / CCHUNK;
  const int nbn = (N + CCHUNK - 1) / CCHUNK;

  hipMemsetAsync(m_enc, 0, (size_t)N * 4, stream);
  hipMemsetAsync(counts, 0, (size_t)N * 4, stream);
  hipMemsetAsync(nmin, 0xFF, (size_t)N * 4, stream);
  hipMemsetAsync(matched_g, 0, (size_t)N, stream);
  hipMemsetAsync(cnts, 0, 64, stream);

  k_raw<<<gridE, TB, 0, stream>>>(x, ei, wsrc, wdst, b, raw, m_enc, counts, N, E);
  k_scan_counts<<<1, WG, 0, stream>>>(counts, dstoff, N);

  // stable sort edges by dst: 2x 8-bit passes (keys < 2^15), A->B->A, result ids in vA
  k_key_dst<<<gridE, TB, 0, stream>>>(ei, kA, vA, E);
  {
    u32 *ka = kA, *va = vA, *kb = kB, *vb = vB;
    for (int p = 0; p < 2; ++p) {
      k_rhist<<<nb, RB, 0, stream>>>(ka, hist, E, nb, p * 8);
      k_rscan<<<1, WG, 0, stream>>>(hist, nb * 256);
      k_rscat<<<nb, RB, 0, stream>>>(ka, va, kb, vb, hist, E, nb, p * 8);
      u32* tk = ka; ka = kb; kb = tk; u32* tv = va; va = vb; vb = tv;
    }
  }

  k_scores<<<gridN, TB, 0, stream>>>(raw, m_enc, counts, dstoff, vA, score, N);

  // stable sort by descending score: 3x 8-bit passes (top byte constant), ids end in vB
  k_key_score<<<gridE, TB, 0, stream>>>(score, kA, vA, E);
  {
    u32 *ka = kA, *va = vA, *kb = kB, *vb = vB;
    for (int p = 0; p < 3; ++p) {
      k_rhist<<<nb, RB, 0, stream>>>(ka, hist, E, nb, p * 8);
      k_rscan<<<1, WG, 0, stream>>>(hist, nb * 256);
      k_rscat<<<nb, RB, 0, stream>>>(ka, va, kb, vb, hist, E, nb, p * 8);
      u32* tk = ka; ka = kb; kb = tk; u32* tv = va; va = vb; vb = tv;
    }
  }

  // prep: per-rank metadata + round-0 node mins (multi-block)
  k_prep<<<gridE, TB, 0, stream>>>(ei, vB, score, pairByRank, scoreByRank,
                                   chosen, nmin, E);

  // pre-round 0 (multi-block): implicit live list; survivors -> liveB, count cnts[8]
  k_choose0<<<gridE, TB, 0, stream>>>(pairByRank, nmin, chosen, matched_g, E);
  k_compact0<<<gridE, TB, 0, stream>>>(pairByRank, matched_g, liveB, nmin, &cnts[8], E);

  // pre-rounds 1..PRROUNDS-1 (multi-block, generic): ping-pong starting from liveB
  u64* Lin = liveB; u64* Lout = liveA;
  for (int r = 1; r < PRROUNDS; ++r) {
    k_chooseR<<<gridE, TB, 0, stream>>>(Lin, &cnts[8 + r - 1], nmin, chosen, matched_g, TAG(r));
    k_compactR<<<gridE, TB, 0, stream>>>(Lin, &cnts[8 + r - 1], matched_g, Lout, nmin,
                                         &cnts[8 + r], TAG(r + 1));
    u64* tmp = Lin; Lin = Lout; Lout = tmp;
  }
  // after the loop Lin holds the round-(PRROUNDS-1) survivors (r4 BUGFIX: was
  // hard-coded to the wrong buffer; 3 compact writes end in liveA for PRROUNDS=4)

  // residual rounds (single block): fixpoint only; writes chosen + matched flags
  k_match<<<1, WG, 0, stream>>>(Lin, Lout, nmin, matched_g, &cnts[8 + PRROUNDS - 1],
                                chosen, N);

  // multi-block cluster-id assignment (identical prefix arithmetic as before)
  k_csum<<<nbc, CB, 0, stream>>>(chosen, csum, E);
  k_nsum<<<nbn, CB, 0, stream>>>(matched_g, nsum, N);
  k_scan2<<<1, 64, 0, stream>>>(csum, nbc, nsum, nbn, cnts);
  k_cassign<<<nbc, CB, 0, stream>>>(chosen, csum, pairByRank, scoreByRank,
                                    cluster, pairA, pairB, cscore, E);
  k_nassign<<<nbn, CB, 0, stream>>>(matched_g, nsum, cnts,
                                    cluster, pairA, pairB, cscore, N);

  hipMemsetAsync(d_out, 0, (size_t)out_size * 4, stream);  // new_x tail rows + new_batch = 0

  k_newx<<<(N * (FDIM / 4) + TB - 1) / TB, TB, 0, stream>>>(x, pairA, pairB, cscore, cnts, (float*)d_out, N);
  k_newei<<<gridE, TB, 0, stream>>>(ei, cluster, cnts, (float*)d_out, N, E);
}

// Round 7
// 496.508 us; speedup vs baseline: 17.5479x; 1.0126x over previous
//
#include <hip/hip_runtime.h>
#include <stdint.h>

typedef unsigned int u32;
typedef unsigned long long u64;
typedef unsigned short u16;
typedef unsigned char u8;

#define FDIM  128
#define NNODE 25000   // LDS sizing; N <= this
#define WG    1024
#define RB    256     // radix block threads
#define EPT   16      // radix elements per thread
#define RCHUNK (RB*EPT) // 4096 = 2^12 elements per radix block
#define RSH   12
// rank fits 18 bits (E <= 262144); round tag in upper 14 bits, decreasing per round
#define KBITS 18
#define TAG(r) (((0x3FFFu - (u32)(r)) << KBITS))
#define PRROUNDS 4      // rounds 0..3 run multi-block; k_match starts at round 4
#define CB 256
#define CEPT 16
#define CCHUNK (CB*CEPT)
#define HSTRIDE (64*256)   // reserved words per hist buffer (nb <= 64)

// ---------- monotone float<->uint encoding (order-preserving, bijective) ----------
__device__ __forceinline__ u32 enc_f32(float f){
  u32 u = __float_as_uint(f);
  return (u & 0x80000000u) ? ~u : (u | 0x80000000u);
}
__device__ __forceinline__ float dec_f32(u32 u){
  u = (u & 0x80000000u) ? (u ^ 0x80000000u) : ~u;
  return __uint_as_float(u);
}

// ---------- XLA CPU GenerateVF32Exp replica (DO NOT TOUCH - validated r1) ----------
__device__ __forceinline__ float xla_expf(float x){
  x = fminf(x,  88.3762626647950f);
  x = fmaxf(x, -88.3762626647949f);
  float fx = floorf(fmaf(x, 1.44269504088896341f, 0.5f));
  float tmp = __fmul_rn(fx, 0.693359375f);
  float zz  = __fmul_rn(fx, -2.12194440e-4f);
  x = __fsub_rn(x, tmp);
  x = __fsub_rn(x, zz);
  float z2 = __fmul_rn(x, x);
  float y = fmaf(1.9875691500E-4f, x, 1.3981999507E-3f);
  y = fmaf(y, x, 8.3334519073E-3f);
  y = fmaf(y, x, 4.1665795894E-2f);
  y = fmaf(y, x, 1.6666665459E-1f);
  y = fmaf(y, x, 5.0000001201E-1f);
  y = fmaf(y, z2, x);
  y = __fadd_rn(y, 1.0f);
  int n = (int)fx;
  float p2n = __uint_as_float((u32)(n + 127) << 23);
  return __fmul_rn(y, p2n);
}

// ---------- per-node dots: ds[v]=x[v]@wsrc, dd[v]=x[v]@wdst ----------
// Strict sequential k-order, unfused mul+add — bit-identical float sequence to the
// per-edge version (dot depends only on the node row).
__global__ __launch_bounds__(256) void k_dots(const float* __restrict__ x,
                      const float* __restrict__ wsrc, const float* __restrict__ wdst,
                      float* __restrict__ ds, float* __restrict__ dd, int N_)
{
  __shared__ float4 w4[64];
  int t = threadIdx.x;
  if (t < 32) w4[t] = ((const float4*)wsrc)[t];
  else if (t < 64) w4[t] = ((const float4*)wdst)[t - 32];
  __syncthreads();
  int v = blockIdx.x * blockDim.x + t;
  if (v >= N_) return;
  const float4* xr = (const float4*)(x + (size_t)v * FDIM);
  float accs = 0.f, accd = 0.f;
  #pragma unroll 4
  for (int k = 0; k < 32; ++k) {
    float4 xv = xr[k], w = w4[k], u = w4[k + 32];
    accs = __fadd_rn(accs, __fmul_rn(xv.x, w.x));
    accs = __fadd_rn(accs, __fmul_rn(xv.y, w.y));
    accs = __fadd_rn(accs, __fmul_rn(xv.z, w.z));
    accs = __fadd_rn(accs, __fmul_rn(xv.w, w.w));
    accd = __fadd_rn(accd, __fmul_rn(xv.x, u.x));
    accd = __fadd_rn(accd, __fmul_rn(xv.y, u.y));
    accd = __fadd_rn(accd, __fmul_rn(xv.z, u.z));
    accd = __fadd_rn(accd, __fmul_rn(xv.w, u.w));
  }
  ds[v] = accs; dd[v] = accd;
}

// ---------- per-edge raw + per-dst max/count + dst-sort keys + pass0 hist ----------
__global__ void k_rawE(const int* __restrict__ ei, const float* __restrict__ ds,
                       const float* __restrict__ dd, const float* __restrict__ b,
                       float* __restrict__ raw, u32* __restrict__ m_enc, u32* __restrict__ counts,
                       u64* __restrict__ kvA, u32* __restrict__ hist_d0, int nb, int E_)
{
  int e = blockIdx.x * blockDim.x + threadIdx.x;
  if (e >= E_) return;
  int s = ei[e], d = ei[E_ + e];
  float r = __fadd_rn(__fadd_rn(ds[s], dd[d]), b[0]);
  raw[e] = r;
  atomicMax(&m_enc[d], enc_f32(r));
  atomicAdd(&counts[d], 1u);
  kvA[e] = ((u64)(u32)d << 32) | (u32)e;
  atomicAdd(&hist_d0[((u32)d & 255u) * nb + (e >> RSH)], 1u);
}

// ---------- exclusive scan of per-dst counts (single block) ----------
__global__ __launch_bounds__(WG) void k_scan_counts(const u32* __restrict__ counts,
                                                    u32* __restrict__ dstoff, int N_)
{
  __shared__ u32 lds[WG];
  int t = threadIdx.x;
  int chunk = (N_ + WG - 1) / WG;
  int lo = t * chunk; if (lo > N_) lo = N_;
  int hi = lo + chunk; if (hi > N_) hi = N_;
  u32 s = 0;
  for (int v = lo; v < hi; ++v) s += counts[v];
  lds[t] = s; __syncthreads();
  for (int off = 1; off < WG; off <<= 1) {
    u32 a = (t >= off) ? lds[t - off] : 0u;
    __syncthreads();
    lds[t] += a;
    __syncthreads();
  }
  u32 run = lds[t] - s;
  for (int v = lo; v < hi; ++v) { dstoff[v] = run; run += counts[v]; }
}

// ---------- radix: scan of one hist buffer (digit-major [256][nb]) ----------
__global__ __launch_bounds__(WG) void k_rscan(u32* __restrict__ a, int m)
{
  __shared__ u32 lds[WG];
  int t = threadIdx.x;
  int chunk = (m + WG - 1) / WG;
  int lo = t * chunk; if (lo > m) lo = m;
  int hi = lo + chunk; if (hi > m) hi = m;
  u32 s = 0;
  for (int i = lo; i < hi; ++i) s += a[i];
  lds[t] = s; __syncthreads();
  for (int off = 1; off < WG; off <<= 1) {
    u32 v = (t >= off) ? lds[t - off] : 0u;
    __syncthreads();
    lds[t] += v;
    __syncthreads();
  }
  u32 run = lds[t] - s;
  for (int i = lo; i < hi; ++i) { u32 c = a[i]; a[i] = run; run += c; }
}

// ---------- radix: stable scatter of u64 kv (key=high32), fused next-pass hist ----------
__global__ __launch_bounds__(RB) void k_rscat(const u64* __restrict__ kvin, u64* __restrict__ kvout,
                                              const u32* __restrict__ base, u32* __restrict__ nexthist,
                                              int n, int nb, int shift, int shift2)
{
  __shared__ u16 h[RB][258];     // [thread][digit], padded
  __shared__ u32 gbase[256];
  int t = threadIdx.x, b = blockIdx.x;
  for (int i = t; i < RB * 258 / 2; i += RB) ((u32*)h)[i] = 0u;
  __syncthreads();
  int lo = b * RCHUNK + t * EPT;
  int hi = lo + EPT; if (hi > n) hi = n;
  for (int i = lo; i < hi; ++i) { u32 d = ((u32)(kvin[i] >> 32) >> shift) & 255u; h[t][d]++; }
  __syncthreads();
  { // thread t owns digit t: exclusive prefix over threads (ranks <= 4096, fits u16)
    u32 run = 0;
    for (int q = 0; q < RB; ++q) { u16 c = h[q][t]; h[q][t] = (u16)run; run += c; }
    gbase[t] = base[(size_t)t * nb + b];
  }
  __syncthreads();
  for (int i = lo; i < hi; ++i) {
    u64 kv = kvin[i];
    u32 key = (u32)(kv >> 32);
    u32 d = (key >> shift) & 255u;
    u32 p = gbase[d] + (u32)h[t][d];
    h[t][d]++;
    kvout[p] = kv;
    if (nexthist) atomicAdd(&nexthist[((key >> shift2) & 255u) * nb + (p >> RSH)], 1u);
  }
}

// ---------- softmax scores: denom accumulated sequentially in edge-id order ----------
__global__ void k_scores(const float* __restrict__ raw, const u32* __restrict__ m_enc,
                         const u32* __restrict__ counts, const u32* __restrict__ dstoff,
                         const u64* __restrict__ kv_bydst, float* __restrict__ score, int N_)
{
  int v = blockIdx.x * blockDim.x + threadIdx.x;
  if (v >= N_) return;
  u32 c = counts[v];
  if (c == 0) return;
  u32 off = dstoff[v];
  float m = dec_f32(m_enc[v]);
  float denom = 0.f;
  for (u32 i = 0; i < c; ++i) {
    u32 e = (u32)kv_bydst[off + i];
    denom = __fadd_rn(denom, xla_expf(__fsub_rn(raw[e], m)));
  }
  for (u32 i = 0; i < c; ++i) {
    u32 e = (u32)kv_bydst[off + i];
    float z = xla_expf(__fsub_rn(raw[e], m));
    score[e] = __fadd_rn(__fdiv_rn(z, denom), 0.5f);
  }
}

// ---------- score-sort keys: key=~enc(score), value=(s<<16|d); pass0 hist fused ----------
__global__ void k_key_score(const float* __restrict__ score, const int* __restrict__ ei,
                            u64* __restrict__ kvB, u32* __restrict__ hist_s0, int nb, int E_)
{
  int e = blockIdx.x * blockDim.x + threadIdx.x;
  if (e >= E_) return;
  u32 key = ~enc_f32(score[e]);   // ascending => descending score; stable => edge id asc
  u32 sd = ((u32)ei[e] << 16) | (u32)ei[E_ + e];
  kvB[e] = ((u64)key << 32) | sd;
  atomicAdd(&hist_s0[(key & 255u) * nb + (e >> RSH)], 1u);
}

// ---------- prep: per-rank metadata from sorted kv + round-0 node mins ----------
// scoreByRank recovered bit-exactly from the sorted key (enc is bijective).
__global__ void k_prep(const u64* __restrict__ kvS,
                       u32* __restrict__ pairByRank, float* __restrict__ scoreByRank,
                       u8* __restrict__ chosen, u32* __restrict__ nmin, int E_)
{
  int k = blockIdx.x * blockDim.x + threadIdx.x;
  if (k >= E_) return;
  u64 kv = kvS[k];
  u32 sd = (u32)kv;
  pairByRank[k] = sd;
  scoreByRank[k] = dec_f32(~(u32)(kv >> 32));
  chosen[k] = 0;
  u32 val = TAG(0) | (u32)k;
  atomicMin(&nmin[sd >> 16], val);
  atomicMin(&nmin[sd & 0xFFFFu], val);
}

// ---------- pre-round 0 (implicit live list = all ranks) ----------
__global__ void k_choose0(const u32* __restrict__ pairByRank, const u32* __restrict__ nmin,
                          u8* __restrict__ chosen, u8* __restrict__ matched_g, int E_)
{
  int k = blockIdx.x * blockDim.x + threadIdx.x;
  if (k >= E_) return;
  u32 sd = pairByRank[k];
  u32 s = sd >> 16, d = sd & 0xFFFFu;
  u32 myval = TAG(0) | (u32)k;
  if (nmin[s] == myval && nmin[d] == myval) { chosen[k] = 1; matched_g[s] = 1; matched_g[d] = 1; }
}

__global__ void k_compact0(const u32* __restrict__ pairByRank, const u8* __restrict__ matched_g,
                           u64* __restrict__ liveOut, u32* __restrict__ nmin,
                           u32* __restrict__ nlive, int E_)
{
  int k = blockIdx.x * blockDim.x + threadIdx.x;
  int lane = threadIdx.x & 63;
  bool liveE = false; u32 s = 0, d = 0;
  if (k < E_) {
    u32 sd = pairByRank[k];
    s = sd >> 16; d = sd & 0xFFFFu;
    liveE = (!matched_g[s] && !matched_g[d]);
  }
  u64 m = __ballot(liveE);
  if (m != 0ull) {
    int leader = __ffsll((long long)m) - 1;
    u32 base = 0;
    if (lane == leader) base = atomicAdd(nlive, (u32)__popcll(m));
    base = (u32)__shfl((int)base, leader);
    if (liveE) {
      u32 pfx = (u32)__popcll(m & ((1ull << lane) - 1ull));
      liveOut[base + pfx] = ((u64)(u32)k << 32) | ((u64)s << 16) | (u64)d;
      u32 nval = TAG(1) | (u32)k;
      atomicMin(&nmin[s], nval);
      atomicMin(&nmin[d], nval);
    }
  }
}

// ---------- generic pre-round r >= 1 (single nmin; tags strictly decrease;
//            kernels stream-serialized) ----------
__global__ void k_chooseR(const u64* __restrict__ liveIn, const u32* __restrict__ nliveIn,
                          const u32* __restrict__ nmin,
                          u8* __restrict__ chosen, u8* __restrict__ matched_g, u32 rtag)
{
  u32 i = blockIdx.x * blockDim.x + threadIdx.x;
  if (i >= *nliveIn) return;
  u64 v = liveIn[i];
  u32 k = (u32)(v >> 32), s = ((u32)v) >> 16, d = (u32)v & 0xFFFFu;
  u32 myval = rtag | k;
  if (nmin[s] == myval && nmin[d] == myval) { chosen[k] = 1; matched_g[s] = 1; matched_g[d] = 1; }
}

__global__ void k_compactR(const u64* __restrict__ liveIn, const u32* __restrict__ nliveIn,
                           const u8* __restrict__ matched_g,
                           u64* __restrict__ liveOut, u32* __restrict__ nmin,
                           u32* __restrict__ nliveOut, u32 ntag)
{
  u32 i = blockIdx.x * blockDim.x + threadIdx.x;
  int lane = threadIdx.x & 63;
  bool liveE = false; u64 v = 0; u32 s = 0, d = 0;
  if (i < *nliveIn) {
    v = liveIn[i];
    s = ((u32)v) >> 16; d = (u32)v & 0xFFFFu;
    liveE = (!matched_g[s] && !matched_g[d]);
  }
  u64 m = __ballot(liveE);
  if (m != 0ull) {
    int leader = __ffsll((long long)m) - 1;
    u32 base = 0;
    if (lane == leader) base = atomicAdd(nliveOut, (u32)__popcll(m));
    base = (u32)__shfl((int)base, leader);
    if (liveE) {
      u32 pfx = (u32)__popcll(m & ((1ull << lane) - 1ull));
      liveOut[base + pfx] = v;
      u32 nval = ntag | (u32)(v >> 32);
      atomicMin(&nmin[s], nval);
      atomicMin(&nmin[d], nval);
    }
  }
}

// ---------- single-block residual fixpoint (rounds >= PRROUNDS) ----------
__global__ __launch_bounds__(WG) void k_match(
    u64* liveA, u64* liveB, const u32* __restrict__ nmin_g, u8* __restrict__ matched_g,
    const u32* __restrict__ nliveIn, u8* __restrict__ chosen, int N_)
{
  __shared__ u32 node_min[NNODE];
  __shared__ u32 s_nlive, s_next;
  const int t = threadIdx.x;
  const int lane = t & 63;

  for (int i = t; i < N_; i += WG) node_min[i] = matched_g[i] ? 0u : nmin_g[i];
  if (t == 0) { s_nlive = *nliveIn; s_next = 0u; }
  __syncthreads();

  u64* LA = liveA; u64* LB = liveB;
  u32 r = PRROUNDS;
  while (true) {
    u32 nl = s_nlive;
    if (nl == 0u || r > 16000u) break;
    const u32 tag  = TAG(r);
    const u32 ntag = TAG(r + 1);

    for (u32 i = (u32)t; i < nl; i += WG) {
      u64 v = LA[i];
      u32 k = (u32)(v >> 32);
      u32 s = ((u32)v) >> 16, d = (u32)v & 0xFFFFu;
      u32 myval = tag | k;
      if (node_min[s] == myval && node_min[d] == myval) {
        chosen[k] = 1; node_min[s] = 0u; node_min[d] = 0u;
      }
    }
    __syncthreads();

    for (u32 i0 = (u32)(t & ~63); i0 < nl; i0 += WG) {
      u32 i = i0 + (u32)lane;
      bool liveE = false; u64 v = 0;
      u32 s = 0, d = 0;
      if (i < nl) {
        v = LA[i];
        s = ((u32)v) >> 16; d = (u32)v & 0xFFFFu;
        liveE = (node_min[s] != 0u && node_min[d] != 0u);
      }
      u64 m = __ballot(liveE);
      if (m != 0ull) {
        int leader = __ffsll((long long)m) - 1;
        u32 baseIdx = 0;
        if (lane == leader) baseIdx = atomicAdd(&s_next, (u32)__popcll(m));
        baseIdx = (u32)__shfl((int)baseIdx, leader);
        if (liveE) {
          u32 pfx = (u32)__popcll(m & ((1ull << lane) - 1ull));
          LB[baseIdx + pfx] = v;
          u32 nval = ntag | (u32)(v >> 32);
          atomicMin(&node_min[s], nval);
          atomicMin(&node_min[d], nval);
        }
      }
    }
    __syncthreads();
    if (t == 0) { s_nlive = s_next; s_next = 0u; }
    { u64* tmp = LA; LA = LB; LB = tmp; }
    ++r;
    __syncthreads();
  }

  for (int i = t; i < N_; i += WG) matched_g[i] = (node_min[i] == 0u) ? 1 : 0;
}

// ---------- fused per-block sums: blocks [0,nbc) -> csum, [nbc,nbc+nbn) -> nsum ----------
__global__ __launch_bounds__(CB) void k_sums(const u8* __restrict__ chosen, u32* __restrict__ csum, int E_,
                                             const u8* __restrict__ matched, u32* __restrict__ nsum, int N_,
                                             int nbc)
{
  __shared__ u32 sh[CB];
  int t = threadIdx.x, b = blockIdx.x;
  const u8* src; int n; u32* dst; int bb;
  if (b < nbc) { src = chosen; n = E_; dst = csum; bb = b; }
  else         { src = matched; n = N_; dst = nsum; bb = b - nbc; }
  int lo = bb * CCHUNK + t * CEPT;
  int hi = lo + CEPT; if (hi > n) hi = n;
  u32 c = 0;
  if (b < nbc) { for (int i = lo; i < hi; ++i) c += src[i]; }
  else         { for (int i = lo; i < hi; ++i) c += (src[i] ? 0u : 1u); }
  sh[t] = c; __syncthreads();
  for (int off = CB / 2; off > 0; off >>= 1) { if (t < off) sh[t] += sh[t + off]; __syncthreads(); }
  if (t == 0) dst[bb] = sh[0];
}

__global__ void k_scan2(u32* __restrict__ csum, int nbc, u32* __restrict__ nsum, int nbn,
                        u32* __restrict__ cnts)
{
  if (threadIdx.x == 0) {
    u32 run = 0;
    for (int i = 0; i < nbc; ++i) { u32 v = csum[i]; csum[i] = run; run += v; }
    cnts[4] = run;                       // totalC (pair clusters)
    u32 run2 = 0;
    for (int i = 0; i < nbn; ++i) { u32 v = nsum[i]; nsum[i] = run2; run2 += v; }
    cnts[3] = run + run2;                // num_clusters
  }
}

// ---------- fused assignment: blocks [0,nbc) pairs, [nbc,nbc+nbn) singletons ----------
__global__ __launch_bounds__(CB) void k_assign(const u8* __restrict__ chosen, const u32* __restrict__ csum,
    const u32* __restrict__ pairByRank, const float* __restrict__ scoreByRank, int E_,
    const u8* __restrict__ matched, const u32* __restrict__ nsum, int N_,
    const u32* __restrict__ cnts,
    int* __restrict__ cluster, u32* __restrict__ pairA, u32* __restrict__ pairB,
    float* __restrict__ cscore, int nbc)
{
  __shared__ u32 sh[CB];
  int t = threadIdx.x, b = blockIdx.x;
  if (b < nbc) {
    int lo = b * CCHUNK + t * CEPT;
    int hi = lo + CEPT; if (hi > E_) hi = E_;
    u32 c = 0;
    for (int i = lo; i < hi; ++i) c += chosen[i];
    u32 mine = c;
    sh[t] = c; __syncthreads();
    for (int off = 1; off < CB; off <<= 1) {
      u32 a = (t >= off) ? sh[t - off] : 0u; __syncthreads();
      sh[t] += a; __syncthreads();
    }
    u32 run = csum[b] + sh[t] - mine;
    for (int i = lo; i < hi; ++i) {
      if (chosen[i]) {
        u32 cc = run++;
        u32 sd = pairByRank[i];
        u32 sv = sd >> 16, dv = sd & 0xFFFFu;
        cluster[sv] = (int)cc; cluster[dv] = (int)cc;
        pairA[cc] = sv; pairB[cc] = dv; cscore[cc] = scoreByRank[i];
      }
    }
  } else {
    int bb = b - nbc;
    int lo = bb * CCHUNK + t * CEPT;
    int hi = lo + CEPT; if (hi > N_) hi = N_;
    u32 c = 0;
    for (int i = lo; i < hi; ++i) c += (matched[i] ? 0u : 1u);
    u32 mine = c;
    sh[t] = c; __syncthreads();
    for (int off = 1; off < CB; off <<= 1) {
      u32 a = (t >= off) ? sh[t - off] : 0u; __syncthreads();
      sh[t] += a; __syncthreads();
    }
    u32 run = cnts[4] + nsum[bb] + sh[t] - mine;
    for (int v = lo; v < hi; ++v) {
      if (!matched[v]) {
        u32 cc = run++;
        cluster[v] = (int)cc;
        pairA[cc] = (u32)v; pairB[cc] = (u32)v; cscore[cc] = 1.0f;
      }
    }
  }
}

// ---------- outputs (fully overwrite d_out; no memset needed) ----------
__global__ void k_newx(const float* __restrict__ x, const u32* __restrict__ pairA,
                       const u32* __restrict__ pairB, const float* __restrict__ cscore,
                       const u32* __restrict__ cnts, float* __restrict__ out, int N_)
{
  int j = blockIdx.x * blockDim.x + threadIdx.x;
  int total = N_ * (FDIM / 4);
  if (j >= total) return;
  u32 c = (u32)(j >> 5);
  int q = (j & 31) * 4;
  float4 o;
  if (c >= cnts[3]) {
    o.x = 0.f; o.y = 0.f; o.z = 0.f; o.w = 0.f;   // tail rows are zero
  } else {
    u32 a = pairA[c], bb = pairB[c];
    float cs = cscore[c];
    const float4 va = *(const float4*)(x + (size_t)a * FDIM + q);
    if (a == bb) {
      o.x = __fmul_rn(va.x, cs); o.y = __fmul_rn(va.y, cs);
      o.z = __fmul_rn(va.z, cs); o.w = __fmul_rn(va.w, cs);
    } else {
      const float4 vb = *(const float4*)(x + (size_t)bb * FDIM + q);
      o.x = __fmul_rn(__fadd_rn(va.x, vb.x), cs);
      o.y = __fmul_rn(__fadd_rn(va.y, vb.y), cs);
      o.z = __fmul_rn(__fadd_rn(va.z, vb.z), cs);
      o.w = __fmul_rn(__fadd_rn(va.w, vb.w), cs);
    }
  }
  *(float4*)(out + (size_t)c * FDIM + q) = o;
}

__global__ void k_newei(const int* __restrict__ ei, const int* __restrict__ cluster,
                        const u32* __restrict__ cnts, float* __restrict__ out, int N_, int E_)
{
  int e = blockIdx.x * blockDim.x + threadIdx.x;
  if (e >= E_) return;
  int c0 = cluster[ei[e]];
  int c1 = cluster[ei[E_ + e]];
  if (c0 == c1) { c0 = -1; c1 = -1; }
  size_t base = (size_t)N_ * FDIM;
  out[base + e] = (float)c0;
  out[base + E_ + e] = (float)c1;
  if (e < N_) out[base + 2 * (size_t)E_ + e] = 0.0f;              // new_batch = 0
  if (e == 0) out[base + 2 * (size_t)E_ + N_] = (float)cnts[3];   // num_clusters
}

extern "C" void kernel_launch(void* const* d_in, const int* in_sizes, int n_in,
                              void* d_out, int out_size, void* d_ws, size_t ws_size,
                              hipStream_t stream)
{
  const float* x    = (const float*)d_in[0];
  const int*   ei   = (const int*)d_in[1];
  const float* wsrc = (const float*)d_in[3];
  const float* wdst = (const float*)d_in[4];
  const float* b    = (const float*)d_in[5];
  const int N = in_sizes[0] / FDIM;
  const int E = in_sizes[1] / 2;

  // workspace layout (u32 words); kvA/kvB 8B-aligned (even word offsets)
  u32* w = (u32*)d_ws;
  float* raw   = (float*)w;      w += E;
  float* score = (float*)w;      w += E;
  u64* kvA = (u64*)w;            w += 2 * E;
  u64* kvB = (u64*)w;            w += 2 * E;
  float* ds = (float*)w;         w += N;
  float* dd = (float*)w;         w += N;
  u32* dstoff = w;               w += N;
  int* cluster = (int*)w;        w += N;
  u32* pairA = w;                w += N;
  u32* pairB = w;                w += N;
  float* cscore = (float*)w;     w += N;
  u32* nmin = w;                 w += N;
  u32* csum = w;                 w += 64;
  u32* nsum = w;                 w += 16;
  // ---- contiguous zero block (one memset) ----
  u32* zeros = w;
  u32* m_enc  = w;               w += N;
  u32* counts = w;               w += N;
  u8*  matched_g = (u8*)w;       w += (N + 3) / 4;
  u32* cnts = w;                 w += 16;
  u32* hist_d0 = w;              w += HSTRIDE;
  u32* hist_d1 = w;              w += HSTRIDE;
  u32* hist_s0 = w;              w += HSTRIDE;
  u32* hist_s1 = w;              w += HSTRIDE;
  u32* hist_s2 = w;              w += HSTRIDE;
  size_t zwords = (size_t)(w - zeros);

  // d_out doubles as scratch for match-phase arrays (fully overwritten at the end)
  u64* liveA = (u64*)d_out;                                  // 2E u32 words
  u64* liveB = (u64*)((u32*)d_out + 2 * (size_t)E);          // 2E words
  u32* pairByRank  = (u32*)d_out + 4 * (size_t)E;            // E words
  float* scoreByRank = (float*)((u32*)d_out + 5 * (size_t)E);// E words
  u8* chosen = (u8*)((u32*)d_out + 6 * (size_t)E);           // E bytes

  const int TB = 256;
  const int gridE = (E + TB - 1) / TB;
  const int gridN = (N + TB - 1) / TB;
  const int nb = (E + RCHUNK - 1) / RCHUNK;     // <= 64
  const int m  = nb * 256;
  const int nbc = (E + CCHUNK - 1) / CCHUNK;
  const int nbn = (N + CCHUNK - 1) / CCHUNK;

  hipMemsetAsync(zeros, 0, zwords * 4, stream);
  hipMemsetAsync(nmin, 0xFF, (size_t)N * 4, stream);

  // per-node dots, then per-edge raw + dst keys (+pass0 hist)
  k_dots<<<gridN, TB, 0, stream>>>(x, wsrc, wdst, ds, dd, N);
  k_rawE<<<gridE, TB, 0, stream>>>(ei, ds, dd, b, raw, m_enc, counts, kvA, hist_d0, nb, E);
  k_scan_counts<<<1, WG, 0, stream>>>(counts, dstoff, N);

  // dst sort: 2 passes (keys < 2^15). A->B (hist fused for pass1) -> A
  k_rscan<<<1, WG, 0, stream>>>(hist_d0, m);
  k_rscat<<<nb, RB, 0, stream>>>(kvA, kvB, hist_d0, hist_d1, E, nb, 0, 8);
  k_rscan<<<1, WG, 0, stream>>>(hist_d1, m);
  k_rscat<<<nb, RB, 0, stream>>>(kvB, kvA, hist_d1, (u32*)0, E, nb, 8, 0);

  k_scores<<<gridN, TB, 0, stream>>>(raw, m_enc, counts, dstoff, kvA, score, N);

  // score sort: 3 passes (top byte constant). B->A->B->A
  k_key_score<<<gridE, TB, 0, stream>>>(score, ei, kvB, hist_s0, nb, E);
  k_rscan<<<1, WG, 0, stream>>>(hist_s0, m);
  k_rscat<<<nb, RB, 0, stream>>>(kvB, kvA, hist_s0, hist_s1, E, nb, 0, 8);
  k_rscan<<<1, WG, 0, stream>>>(hist_s1, m);
  k_rscat<<<nb, RB, 0, stream>>>(kvA, kvB, hist_s1, hist_s2, E, nb, 8, 16);
  k_rscan<<<1, WG, 0, stream>>>(hist_s2, m);
  k_rscat<<<nb, RB, 0, stream>>>(kvB, kvA, hist_s2, (u32*)0, E, nb, 16, 0);

  // prep: per-rank metadata + round-0 node mins
  k_prep<<<gridE, TB, 0, stream>>>(kvA, pairByRank, scoreByRank, chosen, nmin, E);

  // pre-round 0: survivors -> liveB, count cnts[8]
  k_choose0<<<gridE, TB, 0, stream>>>(pairByRank, nmin, chosen, matched_g, E);
  k_compact0<<<gridE, TB, 0, stream>>>(pairByRank, matched_g, liveB, nmin, &cnts[8], E);

  // pre-rounds 1..PRROUNDS-1: ping-pong starting from liveB
  u64* Lin = liveB; u64* Lout = liveA;
  for (int r = 1; r < PRROUNDS; ++r) {
    k_chooseR<<<gridE, TB, 0, stream>>>(Lin, &cnts[8 + r - 1], nmin, chosen, matched_g, TAG(r));
    k_compactR<<<gridE, TB, 0, stream>>>(Lin, &cnts[8 + r - 1], matched_g, Lout, nmin,
                                         &cnts[8 + r], TAG(r + 1));
    u64* tmp = Lin; Lin = Lout; Lout = tmp;
  }

  // residual rounds (single block)
  k_match<<<1, WG, 0, stream>>>(Lin, Lout, nmin, matched_g, &cnts[8 + PRROUNDS - 1],
                                chosen, N);

  // cluster-id assignment (fused sums + fused assigns)
  k_sums<<<nbc + nbn, CB, 0, stream>>>(chosen, csum, E, matched_g, nsum, N, nbc);
  k_scan2<<<1, 64, 0, stream>>>(csum, nbc, nsum, nbn, cnts);
  k_assign<<<nbc + nbn, CB, 0, stream>>>(chosen, csum, pairByRank, scoreByRank, E,
                                         matched_g, nsum, N, cnts,
                                         cluster, pairA, pairB, cscore, nbc);

  // outputs (fully overwrite d_out; scratch regions dead by now)
  k_newx<<<(N * (FDIM / 4) + TB - 1) / TB, TB, 0, stream>>>(x, pairA, pairB, cscore, cnts, (float*)d_out, N);
  k_newei<<<gridE, TB, 0, stream>>>(ei, cluster, cnts, (float*)d_out, N, E);
}